// Round 5
// baseline (289.591 us; speedup 1.0000x reference)
//
#include <hip/hip_runtime.h>
#include <math.h>

#define DIMN 1024
#define NH 8
#define ND 64
#define LSEQ 256
#define HD 512      // NH*ND
#define GRID 256

typedef __attribute__((ext_vector_type(8))) short short8;
typedef __attribute__((ext_vector_type(4))) float f32x4;

__device__ __forceinline__ float2 cmul(float2 a, float2 b){
    return make_float2(a.x*b.x - a.y*b.y, a.x*b.y + a.y*b.x);
}
__device__ __forceinline__ ushort f2bf(float f){
    union { float f; unsigned u; } v; v.f = f;
    unsigned r = v.u + 0x7FFF + ((v.u >> 16) & 1);   // RNE
    return (ushort)(r >> 16);
}

#define ISTR 65
#define ASTR 40
#define BK 32

// ---------- blocked (NB=8) in-place Gauss-Jordan (R11/R14-verified) ----------
__device__ __forceinline__ void inv_gj_blocked(const float* __restrict__ Vr,
        const float* __restrict__ Vi, float2* __restrict__ Vinv,
        int h, int tid, float2* Mx){
    for (int idx = tid; idx < 4096; idx += 512){
        int i = idx >> 6, j = idx & 63;
        Mx[i*ISTR + j] = make_float2(Vr[h*4096 + idx], Vi[h*4096 + idx]);
    }
    __syncthreads();
    const int w = tid >> 6, l = tid & 63;
    const int rbase = w*8;
    for (int kb = 0; kb < 8; ++kb){
        const int k0 = kb*8;
        if (w == 0){
            float2 pr[8];
            #pragma unroll
            for (int m = 0; m < 8; ++m) pr[m] = Mx[l*ISTR + k0 + m];
            #pragma unroll
            for (int k = 0; k < 8; ++k){
                const int gk = k0 + k;
                float2 d; d.x = __shfl(pr[k].x, gk); d.y = __shfl(pr[k].y, gk);
                float im = 1.f/(d.x*d.x + d.y*d.y);
                float2 p = make_float2(d.x*im, -d.y*im);
                float2 spr[8];
                #pragma unroll
                for (int m = 0; m < 8; ++m){
                    float2 t; t.x = __shfl(pr[m].x, gk); t.y = __shfl(pr[m].y, gk);
                    spr[m] = (m == k) ? p : cmul(t, p);
                }
                float2 f = pr[k];
                if (l == gk){
                    #pragma unroll
                    for (int m = 0; m < 8; ++m) pr[m] = spr[m];
                } else {
                    #pragma unroll
                    for (int m = 0; m < 8; ++m){
                        float2 u = cmul(f, spr[m]);
                        if (m == k){ pr[m].x = -u.x;  pr[m].y = -u.y;  }
                        else       { pr[m].x -= u.x;  pr[m].y -= u.y;  }
                    }
                }
            }
            #pragma unroll
            for (int m = 0; m < 8; ++m) Mx[l*ISTR + k0 + m] = pr[m];
        }
        __syncthreads();
        float2 br[8];
        #pragma unroll
        for (int m = 0; m < 8; ++m) br[m] = Mx[(k0+m)*ISTR + l];
        __syncthreads();
        if (((unsigned)(l - k0)) >= 8u){
            #pragma unroll
            for (int rr = 0; rr < 8; ++rr){
                const int r = rbase + rr;
                float2 acc;
                if (((unsigned)(r - k0)) < 8u){ acc.x = 0.f; acc.y = 0.f; }
                else acc = Mx[r*ISTR + l];
                #pragma unroll
                for (int m = 0; m < 8; ++m){
                    float2 Pv = Mx[r*ISTR + k0 + m];
                    acc.x += Pv.x*br[m].x - Pv.y*br[m].y;
                    acc.y += Pv.x*br[m].y + Pv.y*br[m].x;
                }
                Mx[r*ISTR + l] = acc;
            }
        }
        __syncthreads();
    }
    for (int idx = tid; idx < 4096; idx += 512){
        int i = idx >> 6, j = idx & 63;
        Vinv[h*4096 + idx] = Mx[i*ISTR + j];
    }
}

// ---------- W3eff tile (R16-verified): fold V into w_out1 ----------
__device__ __forceinline__ void w3eff_tile(const float* __restrict__ Vr,
        const float* __restrict__ Vi, const float* __restrict__ w3,
        ushort* __restrict__ W3bt, int t, int tid, float* lds){
    const int n0 = (t & 31)*32;
    const int c0 = (t >> 5)*32;
    const int h  = c0 >> 7;
    const int og0 = (c0 & 127) >> 1;
    float* Vbr = lds;            // 64 x 16
    float* Vbi = lds + 1024;     // 64 x 16
    float* Wb  = lds + 2048;     // 128 x 32
    for (int q = tid; q < 1024; q += 512){
        int dd = q >> 4, oo = q & 15;
        Vbr[q] = Vr[(h*64+dd)*64 + og0 + oo];
        Vbi[q] = Vi[(h*64+dd)*64 + og0 + oo];
    }
    for (int q = tid; q < 4096; q += 512){
        int row = q >> 5, nn = q & 31;
        Wb[q] = w3[(h*128 + row)*1024 + n0 + nn];
    }
    __syncthreads();
    const int nn = tid & 31, oo = tid >> 5;    // oo 0..15
    float ar = 0.f, ai = 0.f;
    #pragma unroll 8
    for (int dd = 0; dd < 64; ++dd){
        float vr = Vbr[dd*16 + oo], vi = Vbi[dd*16 + oo];
        float w0 = Wb[(dd*2)*32 + nn], w1v = Wb[(dd*2+1)*32 + nn];
        ar += vr*w0 + vi*w1v;
        ai += -vi*w0 + vr*w1v;
    }
    W3bt[(n0+nn)*1024 + c0 + oo*2 + 0] = f2bf(ar);
    W3bt[(n0+nn)*1024 + c0 + oo*2 + 1] = f2bf(ai);
}

// ---------- device-scope grid barrier, v2 (RELAXED poll — no per-poll cache
// invalidate; single release/acquire fence pair per block). R3's ACQUIRE-poll
// invalidated L2 continuously (FETCH 24->54 MB, 311 us). ----------
__device__ __forceinline__ void gbar(unsigned* cnt, unsigned* gen){
    __syncthreads();
    if (threadIdx.x == 0){
        __threadfence();   // release: write back this XCD's dirty lines
        unsigned g = __hip_atomic_load(gen, __ATOMIC_RELAXED, __HIP_MEMORY_SCOPE_AGENT);
        unsigned old = __hip_atomic_fetch_add(cnt, 1u, __ATOMIC_RELAXED, __HIP_MEMORY_SCOPE_AGENT);
        if (old == GRID-1){
            __hip_atomic_store(cnt, 0u, __ATOMIC_RELAXED, __HIP_MEMORY_SCOPE_AGENT);
            __hip_atomic_fetch_add(gen, 1u, __ATOMIC_RELAXED, __HIP_MEMORY_SCOPE_AGENT);
        } else {
            int fast = 64;
            long spins = 0;
            while (__hip_atomic_load(gen, __ATOMIC_RELAXED, __HIP_MEMORY_SCOPE_AGENT) == g){
                if (fast > 0){ --fast; __builtin_amdgcn_s_sleep(1); }
                else __builtin_amdgcn_s_sleep(16);
                if (++spins > (1l<<22)) break;   // safety valve (never hit normally)
            }
        }
        __threadfence();   // acquire: invalidate so we see other XCDs' writes
    }
    __syncthreads();
}

// ---------- K-split GEMM phase: 32x32 tile per group of KS waves, no staging.
// Fragments are direct 16B/lane global loads (layout == verified gemm_bt read).
// Partial sums reduced through LDS (32 KB), epilogue by ks==0 wave.
// Verified end-to-end in R3 fused and R4 standalone runs. ----------
template<int ACT, int KS>
__device__ __forceinline__ void gemm_phase(const ushort* __restrict__ A,
        const ushort* __restrict__ Bt, const float* __restrict__ bias,
        float* __restrict__ Cf, ushort* __restrict__ Cb,
        float2* __restrict__ XCo, float2* __restrict__ Ao,
        int M, int N, int blk, int tid, float* red){
    constexpr int Kw = 1024/KS;
    constexpr int TPBT = 8/KS;
    const int wave = tid >> 6, l = tid & 63;
    const int ml = l & 15, quad = l >> 4;
    const int lt = wave / KS, ks = wave - lt*KS;
    const int tile = blk*TPBT + lt;
    const int tm = M >> 5;
    const int bm = (tile % tm)*32, bn = (tile / tm)*32;
    const ushort* Ap = A  + (bm + ml)*1024 + ks*Kw + quad*8;
    const ushort* Bp = Bt + (bn + ml)*1024 + ks*Kw + quad*8;

    f32x4 acc[2][2];
    #pragma unroll
    for (int i=0;i<2;++i)
        #pragma unroll
        for (int j=0;j<2;++j) acc[i][j] = (f32x4){0.f,0.f,0.f,0.f};

    short8 ac[2], bc[2];
    ac[0] = *(const short8*)(Ap);
    ac[1] = *(const short8*)(Ap + 16*1024);
    bc[0] = *(const short8*)(Bp);
    bc[1] = *(const short8*)(Bp + 16*1024);

    #pragma unroll
    for (int k0 = 32; k0 < Kw; k0 += 32){
        short8 an[2], bn2[2];
        an[0]  = *(const short8*)(Ap + k0);
        an[1]  = *(const short8*)(Ap + 16*1024 + k0);
        bn2[0] = *(const short8*)(Bp + k0);
        bn2[1] = *(const short8*)(Bp + 16*1024 + k0);
        #pragma unroll
        for (int i=0;i<2;++i)
            #pragma unroll
            for (int j=0;j<2;++j)
                acc[i][j] = __builtin_amdgcn_mfma_f32_16x16x32_bf16(ac[i], bc[j], acc[i][j], 0,0,0);
        ac[0]=an[0]; ac[1]=an[1]; bc[0]=bn2[0]; bc[1]=bn2[1];
    }
    #pragma unroll
    for (int i=0;i<2;++i)
        #pragma unroll
        for (int j=0;j<2;++j)
            acc[i][j] = __builtin_amdgcn_mfma_f32_16x16x32_bf16(ac[i], bc[j], acc[i][j], 0,0,0);

    // partial-sum reduction: red[wave][16][64]
    #pragma unroll
    for (int i=0;i<2;++i)
        #pragma unroll
        for (int j=0;j<2;++j)
            #pragma unroll
            for (int r=0;r<4;++r)
                red[wave*1024 + ((i*2+j)*4+r)*64 + l] = acc[i][j][r];
    __syncthreads();

    if (ks == 0){
        #pragma unroll
        for (int i=0;i<2;++i){
            #pragma unroll
            for (int j=0;j<2;++j){
                const int gcol = bn + j*16 + ml;
                const float bsv = bias[gcol];
                #pragma unroll
                for (int r=0;r<4;++r){
                    float val = bsv;
                    #pragma unroll
                    for (int s=0;s<KS;++s)
                        val += red[(wave+s)*1024 + ((i*2+j)*4+r)*64 + l];
                    const int grow = bm + i*16 + quad*4 + r;
                    if (ACT == 2){
                        float v1 = __shfl_down(val, 1);
                        float v2 = __shfl_down(val, 2);
                        float v3 = __shfl_down(val, 3);
                        if ((l & 3) == 0){
                            int hd = gcol >> 2;
                            XCo[grow*HD + hd] = make_float2(val, v1);
                            float m2 = v2*v2 + v3*v3;
                            float s = sqrtf(m2)/(1.f + m2);
                            Ao[grow*HD + hd] = make_float2(v2*s, v3*s);
                        }
                    } else if (ACT == 1){
                        val *= 1.f/(1.f + expf(-val));
                        Cb[grow*N + gcol] = f2bf(val);
                    } else {
                        Cf[grow*N + gcol] = val;
                    }
                }
            }
        }
    }
}

// ---------- fully-fused persistent kernel: 6 phases, 5 grid barriers ----------
__global__ __launch_bounds__(512, 4) void fused_kernel(
        const float* __restrict__ x,
        const float* __restrict__ hidr, const float* __restrict__ him,
        const float* __restrict__ w1, const float* __restrict__ b1,
        const float* __restrict__ w2, const float* __restrict__ b2,
        const float* __restrict__ w3, const float* __restrict__ b3,
        const float* __restrict__ w4, const float* __restrict__ b4,
        const float* __restrict__ Vr, const float* __restrict__ Vi,
        float* __restrict__ out, int tail_n,
        ushort* __restrict__ x_bf, ushort* __restrict__ w1t,
        ushort* __restrict__ w2t, ushort* __restrict__ w4t,
        ushort* __restrict__ W3bt, float2* __restrict__ Vinv,
        float2* __restrict__ XC, float2* __restrict__ Aseq,
        ushort* __restrict__ t1_bf, ushort* __restrict__ y1_bf,
        float2* __restrict__ S255, unsigned* __restrict__ bar){
    __shared__ __align__(16) char lds_raw[33280];
    const int blk = blockIdx.x;
    const int tid = threadIdx.x;
    unsigned* cnt = bar;
    unsigned* gen = bar + 1;
    ushort* Sb = t1_bf;

    // ---- P0: prep. blocks 0-7: inv; blocks 8-255: transposes + x_bf + W3eff ----
    if (blk < 8){
        inv_gj_blocked(Vr, Vi, Vinv, blk, tid, (float2*)lds_raw);
    } else {
        const int half = tid >> 8;
        for (int u = blk-8; u < 2048; u += 248){
            const float* W; ushort* Wt; int N2; int t;
            if (u < 512)      { W = w1; Wt = w1t; N2 = 1024; t = u*2 + half; }
            else if (u < 1536){ W = w2; Wt = w2t; N2 = 2048; t = (u-512)*2 + half; }
            else              { W = w4; Wt = w4t; N2 = 1024; t = (u-1536)*2 + half; }
            const int tiles_n = N2 >> 5;
            const int n0 = (t % tiles_n) * 32, k0 = (t / tiles_n) * 32;
            float* tile = (float*)lds_raw + half*(32*33);
            const int tx = tid & 31, ty = (tid >> 5) & 7;
            #pragma unroll
            for (int i = 0; i < 4; ++i)
                tile[(ty + i*8)*33 + tx] = W[(k0 + ty + i*8)*N2 + n0 + tx];
            __syncthreads();
            #pragma unroll
            for (int i = 0; i < 4; ++i){
                int r = ty + i*8;
                Wt[(n0 + r)*1024 + k0 + tx] = f2bf(tile[tx*33 + r]);
            }
            __syncthreads();
        }
        for (int u = blk-8; u < 64; u += 248){
            const int base = (u*512 + tid)*2;
            #pragma unroll
            for (int j = 0; j < 2; ++j){
                float4 v = ((const float4*)x)[base + j];
                ushort4 uu; uu.x=f2bf(v.x); uu.y=f2bf(v.y); uu.z=f2bf(v.z); uu.w=f2bf(v.w);
                ((ushort4*)x_bf)[base + j] = uu;
            }
        }
        for (int u = blk-8; u < 1024; u += 248){
            w3eff_tile(Vr, Vi, w3, W3bt, u, tid, (float*)lds_raw);
            __syncthreads();
        }
    }
    gbar(cnt, gen);

    // ---- P1: gemm1  t1 = silu(x @ w1 + b1)  (256 tiles, KS=8) ----
    gemm_phase<1,8>(x_bf, w1t, b1, nullptr, t1_bf, nullptr, nullptr,
                    256, 1024, blk, tid, (float*)lds_raw);
    gbar(cnt, gen);

    // ---- P2: gemm2  (t1 @ w2 + b2) -> XC, Aseq  (512 tiles, KS=4) ----
    gemm_phase<2,4>(t1_bf, w2t, b2, nullptr, nullptr, XC, Aseq,
                    256, 2048, blk, tid, (float*)lds_raw);
    gbar(cnt, gen);

    // ---- P3: upscan (verified logic, LDS re-carved) ----
    {
        float4* buf  = (float4*)lds_raw;                  // [2][2][256] 16 KB
        float2* vrow = (float2*)(lds_raw + 16384);        // [2][64] 1 KB
        float2* inu  = (float2*)(lds_raw + 17408);        // [2]
        const int g = tid >> 8, m = tid & 255;
        const int hn = blk*2 + g;
        const int h = hn >> 6;
        if (m < 64) vrow[g*64 + m] = Vinv[hn*64 + m];
        __syncthreads();
        float2 acc = make_float2(0.f, 0.f);
        const float2* xrow = &XC[m*HD + h*64];
        #pragma unroll 8
        for (int o=0;o<64;++o){
            float2 p = cmul(vrow[g*64 + o], xrow[o]);
            acc.x += p.x; acc.y += p.y;
        }
        if (m == 0){
            float2 i0 = make_float2(0.f, 0.f);
            #pragma unroll 8
            for (int o=0;o<64;++o){
                float2 hv = make_float2(hidr[h*64+o], him[h*64+o]);
                float2 p = cmul(vrow[g*64 + o], hv);
                i0.x += p.x; i0.y += p.y;
            }
            inu[g] = i0;
        }
        float2 a = Aseq[m*HD + hn];
        buf[(0*2+g)*LSEQ + m] = make_float4(a.x, a.y, acc.x, acc.y);
        __syncthreads();
        int pb = 0;
        #pragma unroll
        for (int d = 1; d < LSEQ; d <<= 1){
            float4 cur = buf[(pb*2+g)*LSEQ + m];
            float4 o2 = cur;
            if (m >= d){
                float4 prev = buf[(pb*2+g)*LSEQ + m-d];
                float2 cA = make_float2(cur.x, cur.y), cU = make_float2(cur.z, cur.w);
                float2 pA = make_float2(prev.x, prev.y), pU = make_float2(prev.z, prev.w);
                float2 nA = cmul(cA, pA);
                float2 nU = cmul(cA, pU);
                nU.x += cU.x; nU.y += cU.y;
                o2 = make_float4(nA.x, nA.y, nU.x, nU.y);
            }
            buf[((pb^1)*2+g)*LSEQ + m] = o2;
            pb ^= 1;
            __syncthreads();
        }
        float4 t = buf[(pb*2+g)*LSEQ + m];
        float2 init = inu[g];
        float2 st = cmul(make_float2(t.x, t.y), init);
        st.x += t.z; st.y += t.w;
        Sb[m*DIMN + hn*2]   = f2bf(st.x);
        Sb[m*DIMN + hn*2+1] = f2bf(st.y);
        if (m == LSEQ-1) S255[hn] = st;
    }
    gbar(cnt, gen);

    // ---- P4: gemm3  y1 = silu(Sb @ W3eff + b3)  (256 tiles, KS=8) + hidden tail ----
    gemm_phase<1,8>(Sb, W3bt, b3, nullptr, y1_bf, nullptr, nullptr,
                    256, 1024, blk, tid, (float*)lds_raw);
    if (blk == 0 && (tid >> 6) == 0 && tail_n >= 512){
        const int l = tid & 63;
        float* out_tail = out + LSEQ*DIMN;
        for (int hn = l; hn < 512; hn += 64){
            const int h = hn >> 6;
            float2 acc2 = make_float2(0.f, 0.f);
            #pragma unroll 8
            for (int o = 0; o < 64; ++o){
                float2 v = make_float2(Vr[hn*64+o], Vi[hn*64+o]);
                float2 p = cmul(v, S255[h*64+o]);
                acc2.x += p.x; acc2.y += p.y;
            }
            if (tail_n >= 1024){
                out_tail[hn]       = acc2.x;
                out_tail[512 + hn] = acc2.y;
            } else {
                out_tail[hn] = acc2.x;
            }
        }
    }
    gbar(cnt, gen);

    // ---- P5: gemm4  out = y1 @ w4 + b4  (256 tiles, KS=8) ----
    gemm_phase<0,8>(y1_bf, w4t, b4, out, nullptr, nullptr, nullptr,
                    256, 1024, blk, tid, (float*)lds_raw);
}

// ---------- serial-fallback kernels (R14 path; used only if ws too small) ----------
__global__ __launch_bounds__(512) void inv_kernel(const float* __restrict__ Vr,
                                                  const float* __restrict__ Vi,
                                                  float2* __restrict__ Vinv){
    __shared__ float2 Mx[64*ISTR];
    inv_gj_blocked(Vr, Vi, Vinv, blockIdx.x, threadIdx.x, Mx);
}

__global__ __launch_bounds__(256) void transpose_cvt(const float* __restrict__ W,
                 ushort* __restrict__ Wt, int K, int N){
    __shared__ float tile[32][33];
    const int n0 = blockIdx.x * 32, k0 = blockIdx.y * 32;
    const int tx = threadIdx.x & 31, ty = threadIdx.x >> 5;
    #pragma unroll
    for (int i = 0; i < 4; ++i)
        tile[ty + i*8][tx] = W[(k0 + ty + i*8)*N + n0 + tx];
    __syncthreads();
    #pragma unroll
    for (int i = 0; i < 4; ++i){
        int r = ty + i*8;
        Wt[(n0 + r)*K + k0 + tx] = f2bf(tile[tx][r]);
    }
}

__global__ __launch_bounds__(256) void cvt_bf16_kernel(const float* __restrict__ in,
                                 ushort* __restrict__ o, int n4){
    int i = blockIdx.x*256 + threadIdx.x;
    if (i < n4){
        float4 v = ((const float4*)in)[i];
        ushort4 u; u.x=f2bf(v.x); u.y=f2bf(v.y); u.z=f2bf(v.z); u.w=f2bf(v.w);
        ((ushort4*)o)[i] = u;
    }
}

// ---------- bf16 MFMA GEMM, 64x64 tile (R14-verified). Fallback path only. ----------
#define BM 64
#define BN 64
template<int ACT>
__global__ __launch_bounds__(256) void gemm_bt(const ushort* __restrict__ A,
                 const ushort* __restrict__ Bt, const float* __restrict__ bias,
                 float* __restrict__ Cf, ushort* __restrict__ Cb,
                 float2* __restrict__ XCo, float2* __restrict__ Ao,
                 int M, int N, int K,
                 const float* __restrict__ tVr, const float* __restrict__ tVi,
                 const float2* __restrict__ S255, float* __restrict__ out_tail,
                 int tail_n){
    __shared__ ushort As[BM*ASTR];
    __shared__ ushort Bs[BN*ASTR];
    const int tid = threadIdx.x;
    const int bm = blockIdx.y * BM, bn = blockIdx.x * BN;
    const int wave = tid >> 6, l = tid & 63;
    const int wr = (wave >> 1) * 32, wc = (wave & 1) * 32;
    const int ml = l & 15, quad = l >> 4;

    if (ACT == 0 && out_tail != nullptr && blockIdx.x == 0 && blockIdx.y == 0){
        for (int hn = tid; hn < 512; hn += 256){
            int h = hn >> 6;
            float2 acc2 = make_float2(0.f, 0.f);
            #pragma unroll 8
            for (int o = 0; o < 64; ++o){
                float2 v = make_float2(tVr[hn*64+o], tVi[hn*64+o]);
                float2 p = cmul(v, S255[h*64+o]);
                acc2.x += p.x; acc2.y += p.y;
            }
            if (tail_n >= 1024){
                out_tail[hn]       = acc2.x;
                out_tail[512 + hn] = acc2.y;
            } else if (tail_n >= 512){
                out_tail[hn] = acc2.x;
            }
        }
    }

    f32x4 acc[2][2];
    #pragma unroll
    for (int i=0;i<2;++i)
        #pragma unroll
        for (int j=0;j<2;++j) acc[i][j] = (f32x4){0.f,0.f,0.f,0.f};
    const int c0r = tid >> 2;
    const int c0s = tid & 3;
    for (int k0 = 0; k0 < K; k0 += BK){
        uint4 av = *(const uint4*)&A [(bm + c0r)*K + k0 + c0s*8];
        uint4 bv = *(const uint4*)&Bt[(bn + c0r)*K + k0 + c0s*8];
        __syncthreads();
        *(uint4*)&As[c0r*ASTR + c0s*8] = av;
        *(uint4*)&Bs[c0r*ASTR + c0s*8] = bv;
        __syncthreads();
        short8 af[2], bfv[2];
        #pragma unroll
        for (int f=0; f<2; ++f){
            af[f]  = *(const short8*)&As[(wr + f*16 + ml)*ASTR + quad*8];
            bfv[f] = *(const short8*)&Bs[(wc + f*16 + ml)*ASTR + quad*8];
        }
        #pragma unroll
        for (int i=0;i<2;++i)
            #pragma unroll
            for (int j=0;j<2;++j)
                acc[i][j] = __builtin_amdgcn_mfma_f32_16x16x32_bf16(af[i], bfv[j], acc[i][j], 0,0,0);
    }
    #pragma unroll
    for (int i=0;i<2;++i){
        #pragma unroll
        for (int j=0;j<2;++j){
            const int gcol = bn + wc + j*16 + ml;
            const float bsv = bias[gcol];
            #pragma unroll
            for (int r=0;r<4;++r){
                const int grow = bm + wr + i*16 + quad*4 + r;
                float val = acc[i][j][r] + bsv;
                if (ACT == 2){
                    float v1 = __shfl_down(val, 1);
                    float v2 = __shfl_down(val, 2);
                    float v3 = __shfl_down(val, 3);
                    if ((l & 3) == 0){
                        int hd = gcol >> 2;
                        XCo[grow*HD + hd] = make_float2(val, v1);
                        float m2 = v2*v2 + v3*v3;
                        float s = sqrtf(m2)/(1.f + m2);
                        Ao[grow*HD + hd] = make_float2(v2*s, v3*s);
                    }
                } else if (ACT == 1){
                    val *= 1.f/(1.f + expf(-val));
                    Cb[grow*N + gcol] = f2bf(val);
                } else {
                    Cf[grow*N + gcol] = val;
                }
            }
        }
    }
}

// ---------- fallback-only kernels ----------
__global__ __launch_bounds__(256) void vmul_kernel(const float* __restrict__ Vr,
                            const float* __restrict__ Vi,
                            const float2* __restrict__ S, ushort* __restrict__ hrb,
                            float* __restrict__ out_tail, int tail_n){
    int g = blockIdx.x*256 + threadIdx.x;
    int m = g >> 9, hn = g & 511;
    int h = hn >> 6;
    const float* vr = &Vr[hn*64];
    const float* vi = &Vi[hn*64];
    const float2* srow = &S[m*HD + h*64];
    float2 acc = make_float2(0.f, 0.f);
    #pragma unroll 8
    for (int o=0;o<64;++o){
        float2 v = make_float2(vr[o], vi[o]);
        float2 p = cmul(v, srow[o]);
        acc.x += p.x; acc.y += p.y;
    }
    hrb[m*DIMN + hn*2]   = f2bf(acc.x);
    hrb[m*DIMN + hn*2+1] = f2bf(acc.y);
    if (m == LSEQ-1){
        if (tail_n >= 1024){
            out_tail[hn]       = acc.x;
            out_tail[512 + hn] = acc.y;
        } else if (tail_n >= 512){
            out_tail[hn] = acc.x;
        }
    }
}

__global__ __launch_bounds__(512) void upscan_f32_kernel(const float2* __restrict__ Vinv,
        const float* __restrict__ hidr, const float* __restrict__ him,
        const float2* __restrict__ XC, const float2* __restrict__ Aseq,
        float2* __restrict__ S){
    __shared__ float4 buf[2][2][LSEQ];
    __shared__ float2 vrow[2][64];
    __shared__ float2 inu[2];
    const int b = blockIdx.x;
    const int tid = threadIdx.x;
    const int g = tid >> 8, m = tid & 255;
    const int hn = b*2 + g;
    const int h = hn >> 6;
    if (m < 64) vrow[g][m] = Vinv[hn*64 + m];
    __syncthreads();
    float2 acc = make_float2(0.f, 0.f);
    const float2* xrow = &XC[m*HD + h*64];
    #pragma unroll 8
    for (int o=0;o<64;++o){
        float2 p = cmul(vrow[g][o], xrow[o]);
        acc.x += p.x; acc.y += p.y;
    }
    if (m == 0){
        float2 i0 = make_float2(0.f, 0.f);
        #pragma unroll 8
        for (int o=0;o<64;++o){
            float2 hv = make_float2(hidr[h*64+o], him[h*64+o]);
            float2 p = cmul(vrow[g][o], hv);
            i0.x += p.x; i0.y += p.y;
        }
        inu[g] = i0;
    }
    float2 a = Aseq[m*HD + hn];
    buf[0][g][m] = make_float4(a.x, a.y, acc.x, acc.y);
    __syncthreads();
    int pb = 0;
    #pragma unroll
    for (int d = 1; d < LSEQ; d <<= 1){
        float4 cur = buf[pb][g][m];
        float4 o2 = cur;
        if (m >= d){
            float4 prev = buf[pb][g][m-d];
            float2 cA = make_float2(cur.x, cur.y), cU = make_float2(cur.z, cur.w);
            float2 pA = make_float2(prev.x, prev.y), pU = make_float2(prev.z, prev.w);
            float2 nA = cmul(cA, pA);
            float2 nU = cmul(cA, pU);
            nU.x += cU.x; nU.y += cU.y;
            o2 = make_float4(nA.x, nA.y, nU.x, nU.y);
        }
        buf[pb^1][g][m] = o2;
        pb ^= 1;
        __syncthreads();
    }
    float4 t = buf[pb][g][m];
    float2 init = inu[g];
    float2 st = cmul(make_float2(t.x, t.y), init);
    st.x += t.z; st.y += t.w;
    S[m*HD + hn] = st;
}

extern "C" void kernel_launch(void* const* d_in, const int* in_sizes, int n_in,
                              void* d_out, int out_size, void* d_ws, size_t ws_size,
                              hipStream_t stream) {
    const float* x      = (const float*)d_in[0];
    const float* hidr   = (const float*)d_in[1];
    const float* hidi   = (const float*)d_in[2];
    const float* w_in1  = (const float*)d_in[3];
    const float* b_in1  = (const float*)d_in[4];
    const float* w_in2  = (const float*)d_in[5];
    const float* b_in2  = (const float*)d_in[6];
    const float* w_out1 = (const float*)d_in[7];
    const float* b_out1 = (const float*)d_in[8];
    const float* w_out2 = (const float*)d_in[9];
    const float* b_out2 = (const float*)d_in[10];
    const float* Vr     = (const float*)d_in[11];
    const float* Vi     = (const float*)d_in[12];
    float* out = (float*)d_out;
    const int tail_n = out_size - LSEQ*DIMN;
    char* ws = (char*)d_ws;

    if (ws_size >= 14946304u){
        // lifetime-aliased layout (12.3 MB used + barrier @14 MB):
        //   Vinv  [0, 256K)            P0->P3
        //   w2t   [256K, 4.25M)        P0->P2
        //   W3bt  [4.25M, 6.25M)       P0->P4
        //   w4t   [6.25M, 8.25M)       P0->P5
        //   w1t   [8.25M, 10.25M)      P0->P1   } reused P2+: XC(1M)+Aseq(1M)
        //   x_bf  [10.25M, 10.75M)     P0->P1   } reused P3+: S255(4K)
        //   t1_bf [10.75M, 11.25M)     P1->P2   } reused P3+: Sb
        //   y1_bf [11.25M, 11.75M)     P4->P5
        //   bar   [14.0M, 14.0M+64)   grid-barrier state (memset each launch)
        float2* Vinv  = (float2*)(ws + 0);
        ushort* w2t   = (ushort*)(ws + 262144);
        ushort* W3bt  = (ushort*)(ws + 4456448);
        ushort* w4t   = (ushort*)(ws + 6553600);
        ushort* w1t   = (ushort*)(ws + 8650752);
        float2* XC    = (float2*)(ws + 8650752);
        float2* Aseq  = (float2*)(ws + 9699328);
        ushort* x_bf  = (ushort*)(ws + 10747904);
        float2* S255  = (float2*)(ws + 10747904);
        ushort* t1_bf = (ushort*)(ws + 11272192);
        ushort* y1_bf = (ushort*)(ws + 11796480);
        unsigned* bar = (unsigned*)(ws + 14680064);

        hipMemsetAsync(ws + 14680064, 0, 64, stream);
        fused_kernel<<<GRID, 512, 0, stream>>>(x, hidr, hidi,
                w_in1, b_in1, w_in2, b_in2, w_out1, b_out1, w_out2, b_out2,
                Vr, Vi, out, tail_n,
                x_bf, w1t, w2t, w4t, W3bt, Vinv, XC, Aseq, t1_bf, y1_bf,
                S255, bar);
    } else {
        // ---- R14 fallback: serial prep + full vmul path ----
        float2* Vinv  = (float2*)(ws + 0);
        ushort* wt    = (ushort*)(ws + 262144);
        ushort* x_bf  = (ushort*)(ws + 4456448);
        ushort* t1_bf = (ushort*)(ws + 4980736);
        float2* XC    = (float2*)(ws + 5505024);
        float2* Aseq  = (float2*)(ws + 6553600);
        float2* S     = (float2*)(ws + 7602176);
        ushort* y1_bf = x_bf;
        ushort* hr_bf = t1_bf;

        inv_kernel<<<NH, 512, 0, stream>>>(Vr, Vi, Vinv);
        cvt_bf16_kernel<<<LSEQ*DIMN/4/256, 256, 0, stream>>>(x, x_bf, LSEQ*DIMN/4);
        transpose_cvt<<<dim3(32,32), 256, 0, stream>>>(w_in1, wt, DIMN, DIMN);
        gemm_bt<1><<<dim3(16,4), 256, 0, stream>>>(x_bf, wt, b_in1, nullptr, t1_bf,
                nullptr, nullptr, LSEQ, DIMN, DIMN, nullptr, nullptr, nullptr, nullptr, 0);
        transpose_cvt<<<dim3(64,32), 256, 0, stream>>>(w_in2, wt, DIMN, 2048);
        gemm_bt<2><<<dim3(32,4), 256, 0, stream>>>(t1_bf, wt, b_in2, nullptr, nullptr,
                XC, Aseq, LSEQ, 2048, DIMN, nullptr, nullptr, nullptr, nullptr, 0);
        upscan_f32_kernel<<<256, 512, 0, stream>>>(Vinv, hidr, hidi, XC, Aseq, S);
        vmul_kernel<<<LSEQ*HD/256, 256, 0, stream>>>(Vr, Vi, S, hr_bf, out + LSEQ*DIMN, tail_n);
        transpose_cvt<<<dim3(32,32), 256, 0, stream>>>(w_out1, wt, DIMN, DIMN);
        gemm_bt<1><<<dim3(16,4), 256, 0, stream>>>(hr_bf, wt, b_out1, nullptr, y1_bf,
                nullptr, nullptr, LSEQ, DIMN, DIMN, nullptr, nullptr, nullptr, nullptr, 0);
        transpose_cvt<<<dim3(32,32), 256, 0, stream>>>(w_out2, wt, DIMN, DIMN);
        gemm_bt<0><<<dim3(16,4), 256, 0, stream>>>(y1_bf, wt, b_out2, out, nullptr,
                nullptr, nullptr, LSEQ, DIMN, DIMN, nullptr, nullptr, nullptr, nullptr, 0);
    }
}

// Round 9
// 202.009 us; speedup vs baseline: 1.4336x; 1.4336x over previous
//
#include <hip/hip_runtime.h>
#include <math.h>

#define DIMN 1024
#define NH 8
#define ND 64
#define LSEQ 256
#define HD 512      // NH*ND

typedef __attribute__((ext_vector_type(8))) short short8;
typedef __attribute__((ext_vector_type(4))) float f32x4;

__device__ __forceinline__ float2 cmul(float2 a, float2 b){
    return make_float2(a.x*b.x - a.y*b.y, a.x*b.y + a.y*b.x);
}
__device__ __forceinline__ ushort f2bf(float f){
    union { float f; unsigned u; } v; v.f = f;
    unsigned r = v.u + 0x7FFF + ((v.u >> 16) & 1);   // RNE
    return (ushort)(r >> 16);
}

#define ISTR 65
#define ASTR 40
#define BK 32

// ---------- blocked (NB=8) in-place Gauss-Jordan (R11/R14-verified, verbatim) ----------
__device__ __forceinline__ void inv_gj_blocked(const float* __restrict__ Vr,
        const float* __restrict__ Vi, float2* __restrict__ Vinv,
        int h, int tid, float2* Mx){
    for (int idx = tid; idx < 4096; idx += 512){
        int i = idx >> 6, j = idx & 63;
        Mx[i*ISTR + j] = make_float2(Vr[h*4096 + idx], Vi[h*4096 + idx]);
    }
    __syncthreads();
    const int w = tid >> 6, l = tid & 63;
    const int rbase = w*8;
    for (int kb = 0; kb < 8; ++kb){
        const int k0 = kb*8;
        if (w == 0){
            float2 pr[8];
            #pragma unroll
            for (int m = 0; m < 8; ++m) pr[m] = Mx[l*ISTR + k0 + m];
            #pragma unroll
            for (int k = 0; k < 8; ++k){
                const int gk = k0 + k;
                float2 d; d.x = __shfl(pr[k].x, gk); d.y = __shfl(pr[k].y, gk);
                float im = 1.f/(d.x*d.x + d.y*d.y);
                float2 p = make_float2(d.x*im, -d.y*im);
                float2 spr[8];
                #pragma unroll
                for (int m = 0; m < 8; ++m){
                    float2 t; t.x = __shfl(pr[m].x, gk); t.y = __shfl(pr[m].y, gk);
                    spr[m] = (m == k) ? p : cmul(t, p);
                }
                float2 f = pr[k];
                if (l == gk){
                    #pragma unroll
                    for (int m = 0; m < 8; ++m) pr[m] = spr[m];
                } else {
                    #pragma unroll
                    for (int m = 0; m < 8; ++m){
                        float2 u = cmul(f, spr[m]);
                        if (m == k){ pr[m].x = -u.x;  pr[m].y = -u.y;  }
                        else       { pr[m].x -= u.x;  pr[m].y -= u.y;  }
                    }
                }
            }
            #pragma unroll
            for (int m = 0; m < 8; ++m) Mx[l*ISTR + k0 + m] = pr[m];
        }
        __syncthreads();
        float2 br[8];
        #pragma unroll
        for (int m = 0; m < 8; ++m) br[m] = Mx[(k0+m)*ISTR + l];
        __syncthreads();
        if (((unsigned)(l - k0)) >= 8u){
            #pragma unroll
            for (int rr = 0; rr < 8; ++rr){
                const int r = rbase + rr;
                float2 acc;
                if (((unsigned)(r - k0)) < 8u){ acc.x = 0.f; acc.y = 0.f; }
                else acc = Mx[r*ISTR + l];
                #pragma unroll
                for (int m = 0; m < 8; ++m){
                    float2 Pv = Mx[r*ISTR + k0 + m];
                    acc.x += Pv.x*br[m].x - Pv.y*br[m].y;
                    acc.y += Pv.x*br[m].y + Pv.y*br[m].x;
                }
                Mx[r*ISTR + l] = acc;
            }
        }
        __syncthreads();
    }
    for (int idx = tid; idx < 4096; idx += 512){
        int i = idx >> 6, j = idx & 63;
        Vinv[h*4096 + idx] = Mx[i*ISTR + j];
    }
}

// ---------- W3eff tile (R16-verified): fold V into w_out1 ----------
__device__ __forceinline__ void w3eff_tile(const float* __restrict__ Vr,
        const float* __restrict__ Vi, const float* __restrict__ w3,
        ushort* __restrict__ W3bt, int t, int tid, float* lds){
    const int n0 = (t & 31)*32;
    const int c0 = (t >> 5)*32;
    const int h  = c0 >> 7;
    const int og0 = (c0 & 127) >> 1;
    float* Vbr = lds;            // 64 x 16
    float* Vbi = lds + 1024;     // 64 x 16
    float* Wb  = lds + 2048;     // 128 x 32
    for (int q = tid; q < 1024; q += 512){
        int dd = q >> 4, oo = q & 15;
        Vbr[q] = Vr[(h*64+dd)*64 + og0 + oo];
        Vbi[q] = Vi[(h*64+dd)*64 + og0 + oo];
    }
    for (int q = tid; q < 4096; q += 512){
        int row = q >> 5, nn = q & 31;
        Wb[q] = w3[(h*128 + row)*1024 + n0 + nn];
    }
    __syncthreads();
    const int nn = tid & 31, oo = tid >> 5;    // oo 0..15
    float ar = 0.f, ai = 0.f;
    #pragma unroll 8
    for (int dd = 0; dd < 64; ++dd){
        float vr = Vbr[dd*16 + oo], vi = Vbi[dd*16 + oo];
        float w0 = Wb[(dd*2)*32 + nn], w1v = Wb[(dd*2+1)*32 + nn];
        ar += vr*w0 + vi*w1v;
        ai += -vi*w0 + vr*w1v;
    }
    W3bt[(n0+nn)*1024 + c0 + oo*2 + 0] = f2bf(ar);
    W3bt[(n0+nn)*1024 + c0 + oo*2 + 1] = f2bf(ai);
}

// ---------- prep (slim): inv + w1t + w2t + x->bf16 ----------
// blocks [0,8): inv (monolithic, verified); [8,520): w1t; [520,1544): w2t;
// [1544,1608): x cvt.  (W3eff and w4t moved to ride on D2/D3.)
__global__ __launch_bounds__(512) void prep_kernel(
        const float* __restrict__ x,
        const float* __restrict__ w1, const float* __restrict__ w2,
        const float* __restrict__ Vr, const float* __restrict__ Vi,
        ushort* __restrict__ x_bf,
        ushort* __restrict__ w1t, ushort* __restrict__ w2t,
        float2* __restrict__ Vinv){
    __shared__ __align__(16) char lds_raw[33280];
    const int b = blockIdx.x;
    const int tid = threadIdx.x;
    const int half = tid >> 8;

    if (b < 8){
        inv_gj_blocked(Vr, Vi, Vinv, b, tid, (float2*)lds_raw);
        return;
    }
    int u = b - 8;
    if (u < 1536){
        const float* W; ushort* Wt; const int K = 1024; int N; int t;
        if (u < 512){ W = w1; Wt = w1t; N = 1024; t = u*2 + half; }
        else        { W = w2; Wt = w2t; N = 2048; t = (u-512)*2 + half; }
        const int tiles_n = N >> 5;
        const int n0 = (t % tiles_n) * 32, k0 = (t / tiles_n) * 32;
        float* tile = (float*)lds_raw + half*(32*33);
        const int tx = tid & 31, ty = (tid >> 5) & 7;
        #pragma unroll
        for (int i = 0; i < 4; ++i)
            tile[(ty + i*8)*33 + tx] = W[(k0 + ty + i*8)*N + n0 + tx];
        __syncthreads();
        #pragma unroll
        for (int i = 0; i < 4; ++i){
            int r = ty + i*8;
            Wt[(n0 + r)*K + k0 + tx] = f2bf(tile[tx*33 + r]);
        }
        return;
    }
    u -= 1536;
    // u < 64: x -> bf16, 64 blocks * 512 thr * 2 float4
    const int base = (u*512 + tid)*2;
    #pragma unroll
    for (int j = 0; j < 2; ++j){
        float4 v = ((const float4*)x)[base + j];
        ushort4 uu; uu.x=f2bf(v.x); uu.y=f2bf(v.y); uu.z=f2bf(v.z); uu.w=f2bf(v.w);
        ((ushort4*)x_bf)[base + j] = uu;
    }
}

// ---------- K-split GEMM phase (verbatim R4-verified) ----------
template<int ACT, int KS>
__device__ __forceinline__ void gemm_phase(const ushort* __restrict__ A,
        const ushort* __restrict__ Bt, const float* __restrict__ bias,
        float* __restrict__ Cf, ushort* __restrict__ Cb,
        float2* __restrict__ XCo, float2* __restrict__ Ao,
        int M, int N, int blk, int tid, float* red){
    constexpr int Kw = 1024/KS;
    constexpr int TPBT = 8/KS;
    const int wave = tid >> 6, l = tid & 63;
    const int ml = l & 15, quad = l >> 4;
    const int lt = wave / KS, ks = wave - lt*KS;
    const int tile = blk*TPBT + lt;
    const int tm = M >> 5;
    const int bm = (tile % tm)*32, bn = (tile / tm)*32;
    const ushort* Ap = A  + (bm + ml)*1024 + ks*Kw + quad*8;
    const ushort* Bp = Bt + (bn + ml)*1024 + ks*Kw + quad*8;

    f32x4 acc[2][2];
    #pragma unroll
    for (int i=0;i<2;++i)
        #pragma unroll
        for (int j=0;j<2;++j) acc[i][j] = (f32x4){0.f,0.f,0.f,0.f};

    short8 ac[2], bc[2];
    ac[0] = *(const short8*)(Ap);
    ac[1] = *(const short8*)(Ap + 16*1024);
    bc[0] = *(const short8*)(Bp);
    bc[1] = *(const short8*)(Bp + 16*1024);

    #pragma unroll
    for (int k0 = 32; k0 < Kw; k0 += 32){
        short8 an[2], bn2[2];
        an[0]  = *(const short8*)(Ap + k0);
        an[1]  = *(const short8*)(Ap + 16*1024 + k0);
        bn2[0] = *(const short8*)(Bp + k0);
        bn2[1] = *(const short8*)(Bp + 16*1024 + k0);
        #pragma unroll
        for (int i=0;i<2;++i)
            #pragma unroll
            for (int j=0;j<2;++j)
                acc[i][j] = __builtin_amdgcn_mfma_f32_16x16x32_bf16(ac[i], bc[j], acc[i][j], 0,0,0);
        ac[0]=an[0]; ac[1]=an[1]; bc[0]=bn2[0]; bc[1]=bn2[1];
    }
    #pragma unroll
    for (int i=0;i<2;++i)
        #pragma unroll
        for (int j=0;j<2;++j)
            acc[i][j] = __builtin_amdgcn_mfma_f32_16x16x32_bf16(ac[i], bc[j], acc[i][j], 0,0,0);

    // partial-sum reduction: red[wave][16][64]
    #pragma unroll
    for (int i=0;i<2;++i)
        #pragma unroll
        for (int j=0;j<2;++j)
            #pragma unroll
            for (int r=0;r<4;++r)
                red[wave*1024 + ((i*2+j)*4+r)*64 + l] = acc[i][j][r];
    __syncthreads();

    if (ks == 0){
        #pragma unroll
        for (int i=0;i<2;++i){
            #pragma unroll
            for (int j=0;j<2;++j){
                const int gcol = bn + j*16 + ml;
                const float bsv = bias[gcol];
                #pragma unroll
                for (int r=0;r<4;++r){
                    float val = bsv;
                    #pragma unroll
                    for (int s=0;s<KS;++s)
                        val += red[(wave+s)*1024 + ((i*2+j)*4+r)*64 + l];
                    const int grow = bm + i*16 + quad*4 + r;
                    if (ACT == 2){
                        float v1 = __shfl_down(val, 1);
                        float v2 = __shfl_down(val, 2);
                        float v3 = __shfl_down(val, 3);
                        if ((l & 3) == 0){
                            int hd = gcol >> 2;
                            XCo[grow*HD + hd] = make_float2(val, v1);
                            float m2 = v2*v2 + v3*v3;
                            float s = sqrtf(m2)/(1.f + m2);
                            Ao[grow*HD + hd] = make_float2(v2*s, v3*s);
                        }
                    } else if (ACT == 1){
                        val *= 1.f/(1.f + expf(-val));
                        Cb[grow*N + gcol] = f2bf(val);
                    } else {
                        Cf[grow*N + gcol] = val;
                    }
                }
            }
        }
    }
}

// ---------- GEMM dispatch with independent rider blocks:
// RIDE==1: blocks >= ntb run w3eff_tile (u in [0,1024)).
// RIDE==2: blocks >= ntb run the w4 transpose (u in [0,512), 2 tiles/block).
// Rider code bodies are verbatim from the verified prep_kernel. ----------
template<int ACT, int KS, int RIDE>
__global__ __launch_bounds__(512) void gemm_ride(const ushort* __restrict__ A,
        const ushort* __restrict__ Bt, const float* __restrict__ bias,
        float* __restrict__ Cf, ushort* __restrict__ Cb,
        float2* __restrict__ XCo, float2* __restrict__ Ao,
        int M, int N,
        const float* __restrict__ Vr, const float* __restrict__ Vi,
        const float* __restrict__ w3, ushort* __restrict__ W3bt,
        const float* __restrict__ w4, ushort* __restrict__ w4t){
    __shared__ __align__(16) char lds_raw[33280];
    const int nt = (M >> 5) * (N >> 5);
    const int ntb = nt / (8/KS);
    if ((int)blockIdx.x >= ntb){
        const int u = (int)blockIdx.x - ntb;
        const int tid = threadIdx.x;
        if (RIDE == 1){
            w3eff_tile(Vr, Vi, w3, W3bt, u, tid, (float*)lds_raw);
        } else {
            const int half = tid >> 8;
            const int t = u*2 + half;
            const int n0 = (t & 31)*32, k0 = (t >> 5)*32;
            float* tile = (float*)lds_raw + half*(32*33);
            const int tx = tid & 31, ty = (tid >> 5) & 7;
            #pragma unroll
            for (int i = 0; i < 4; ++i)
                tile[(ty + i*8)*33 + tx] = w4[(k0 + ty + i*8)*1024 + n0 + tx];
            __syncthreads();
            #pragma unroll
            for (int i = 0; i < 4; ++i){
                int r = ty + i*8;
                w4t[(n0 + r)*1024 + k0 + tx] = f2bf(tile[tx*33 + r]);
            }
        }
        return;
    }
    gemm_phase<ACT, KS>(A, Bt, bias, Cf, Cb, XCo, Ao, M, N,
                        blockIdx.x, threadIdx.x, (float*)lds_raw);
}

// ---------- standalone K-split GEMM dispatch (verbatim R4). Tail block
// computes the hidden_next tail (gemm3 only, out_tail != nullptr). ----------
template<int ACT, int KS>
__global__ __launch_bounds__(512) void gemm_ks(const ushort* __restrict__ A,
        const ushort* __restrict__ Bt, const float* __restrict__ bias,
        float* __restrict__ Cf, ushort* __restrict__ Cb,
        float2* __restrict__ XCo, float2* __restrict__ Ao,
        int M, int N,
        const float* __restrict__ tVr, const float* __restrict__ tVi,
        const float2* __restrict__ S255, float* __restrict__ out_tail,
        int tail_n){
    __shared__ float red[8*1024];
    const int nt = (M >> 5) * (N >> 5);
    const int ntb = nt / (8/KS);
    if (out_tail != nullptr && blockIdx.x >= ntb){
        if ((threadIdx.x >> 6) == 0 && tail_n >= 512){
            const int l = threadIdx.x & 63;
            for (int hn = l; hn < 512; hn += 64){
                const int h = hn >> 6;
                float2 acc2 = make_float2(0.f, 0.f);
                #pragma unroll 8
                for (int o = 0; o < 64; ++o){
                    float2 v = make_float2(tVr[hn*64+o], tVi[hn*64+o]);
                    float2 p = cmul(v, S255[h*64+o]);
                    acc2.x += p.x; acc2.y += p.y;
                }
                if (tail_n >= 1024){
                    out_tail[hn]       = acc2.x;
                    out_tail[512 + hn] = acc2.y;
                } else {
                    out_tail[hn] = acc2.x;
                }
            }
        }
        return;
    }
    gemm_phase<ACT, KS>(A, Bt, bias, Cf, Cb, XCo, Ao, M, N,
                        blockIdx.x, threadIdx.x, red);
}

// ---------- serial-fallback kernels (R14 path; used only if ws too small) ----------
__global__ __launch_bounds__(512) void inv_kernel(const float* __restrict__ Vr,
                                                  const float* __restrict__ Vi,
                                                  float2* __restrict__ Vinv){
    __shared__ float2 Mx[64*ISTR];
    inv_gj_blocked(Vr, Vi, Vinv, blockIdx.x, threadIdx.x, Mx);
}

__global__ __launch_bounds__(256) void transpose_cvt(const float* __restrict__ W,
                 ushort* __restrict__ Wt, int K, int N){
    __shared__ float tile[32][33];
    const int n0 = blockIdx.x * 32, k0 = blockIdx.y * 32;
    const int tx = threadIdx.x & 31, ty = threadIdx.x >> 5;
    #pragma unroll
    for (int i = 0; i < 4; ++i)
        tile[ty + i*8][tx] = W[(k0 + ty + i*8)*N + n0 + tx];
    __syncthreads();
    #pragma unroll
    for (int i = 0; i < 4; ++i){
        int r = ty + i*8;
        Wt[(n0 + r)*K + k0 + tx] = f2bf(tile[tx][r]);
    }
}

__global__ __launch_bounds__(256) void cvt_bf16_kernel(const float* __restrict__ in,
                                 ushort* __restrict__ o, int n4){
    int i = blockIdx.x*256 + threadIdx.x;
    if (i < n4){
        float4 v = ((const float4*)in)[i];
        ushort4 u; u.x=f2bf(v.x); u.y=f2bf(v.y); u.z=f2bf(v.z); u.w=f2bf(v.w);
        ((ushort4*)o)[i] = u;
    }
}

// ---------- bf16 MFMA GEMM, 64x64 tile (R14-verified). Fallback path only. ----------
#define BM 64
#define BN 64
template<int ACT>
__global__ __launch_bounds__(256) void gemm_bt(const ushort* __restrict__ A,
                 const ushort* __restrict__ Bt, const float* __restrict__ bias,
                 float* __restrict__ Cf, ushort* __restrict__ Cb,
                 float2* __restrict__ XCo, float2* __restrict__ Ao,
                 int M, int N, int K,
                 const float* __restrict__ tVr, const float* __restrict__ tVi,
                 const float2* __restrict__ S255, float* __restrict__ out_tail,
                 int tail_n){
    __shared__ ushort As[BM*ASTR];
    __shared__ ushort Bs[BN*ASTR];
    const int tid = threadIdx.x;
    const int bm = blockIdx.y * BM, bn = blockIdx.x * BN;
    const int wave = tid >> 6, l = tid & 63;
    const int wr = (wave >> 1) * 32, wc = (wave & 1) * 32;
    const int ml = l & 15, quad = l >> 4;

    if (ACT == 0 && out_tail != nullptr && blockIdx.x == 0 && blockIdx.y == 0){
        for (int hn = tid; hn < 512; hn += 256){
            int h = hn >> 6;
            float2 acc2 = make_float2(0.f, 0.f);
            #pragma unroll 8
            for (int o = 0; o < 64; ++o){
                float2 v = make_float2(tVr[hn*64+o], tVi[hn*64+o]);
                float2 p = cmul(v, S255[h*64+o]);
                acc2.x += p.x; acc2.y += p.y;
            }
            if (tail_n >= 1024){
                out_tail[hn]       = acc2.x;
                out_tail[512 + hn] = acc2.y;
            } else if (tail_n >= 512){
                out_tail[hn] = acc2.x;
            }
        }
    }

    f32x4 acc[2][2];
    #pragma unroll
    for (int i=0;i<2;++i)
        #pragma unroll
        for (int j=0;j<2;++j) acc[i][j] = (f32x4){0.f,0.f,0.f,0.f};
    const int c0r = tid >> 2;
    const int c0s = tid & 3;
    for (int k0 = 0; k0 < K; k0 += BK){
        uint4 av = *(const uint4*)&A [(bm + c0r)*K + k0 + c0s*8];
        uint4 bv = *(const uint4*)&Bt[(bn + c0r)*K + k0 + c0s*8];
        __syncthreads();
        *(uint4*)&As[c0r*ASTR + c0s*8] = av;
        *(uint4*)&Bs[c0r*ASTR + c0s*8] = bv;
        __syncthreads();
        short8 af[2], bfv[2];
        #pragma unroll
        for (int f=0; f<2; ++f){
            af[f]  = *(const short8*)&As[(wr + f*16 + ml)*ASTR + quad*8];
            bfv[f] = *(const short8*)&Bs[(wc + f*16 + ml)*ASTR + quad*8];
        }
        #pragma unroll
        for (int i=0;i<2;++i)
            #pragma unroll
            for (int j=0;j<2;++j)
                acc[i][j] = __builtin_amdgcn_mfma_f32_16x16x32_bf16(af[i], bfv[j], acc[i][j], 0,0,0);
    }
    #pragma unroll
    for (int i=0;i<2;++i){
        #pragma unroll
        for (int j=0;j<2;++j){
            const int gcol = bn + wc + j*16 + ml;
            const float bsv = bias[gcol];
            #pragma unroll
            for (int r=0;r<4;++r){
                const int grow = bm + wr + i*16 + quad*4 + r;
                float val = acc[i][j][r] + bsv;
                if (ACT == 2){
                    float v1 = __shfl_down(val, 1);
                    float v2 = __shfl_down(val, 2);
                    float v3 = __shfl_down(val, 3);
                    if ((l & 3) == 0){
                        int hd = gcol >> 2;
                        XCo[grow*HD + hd] = make_float2(val, v1);
                        float m2 = v2*v2 + v3*v3;
                        float s = sqrtf(m2)/(1.f + m2);
                        Ao[grow*HD + hd] = make_float2(v2*s, v3*s);
                    }
                } else if (ACT == 1){
                    val *= 1.f/(1.f + expf(-val));
                    Cb[grow*N + gcol] = f2bf(val);
                } else {
                    Cf[grow*N + gcol] = val;
                }
            }
        }
    }
}

// ---------- fused uext + parallel scan; writes Sb (bf16, hr-layout) + S255 fp32 ----------
__global__ __launch_bounds__(512) void upscan_kernel(const float2* __restrict__ Vinv,
        const float* __restrict__ hidr, const float* __restrict__ him,
        const float2* __restrict__ XC, const float2* __restrict__ Aseq,
        ushort* __restrict__ Sb, float2* __restrict__ S255){
    __shared__ float4 buf[2][2][LSEQ];
    __shared__ float2 vrow[2][64];
    __shared__ float2 inu[2];
    const int b = blockIdx.x;
    const int tid = threadIdx.x;
    const int g = tid >> 8, m = tid & 255;
    const int hn = b*2 + g;
    const int h = hn >> 6;
    if (m < 64) vrow[g][m] = Vinv[hn*64 + m];
    __syncthreads();
    float2 acc = make_float2(0.f, 0.f);
    const float2* xrow = &XC[m*HD + h*64];
    #pragma unroll 8
    for (int o=0;o<64;++o){
        float2 p = cmul(vrow[g][o], xrow[o]);
        acc.x += p.x; acc.y += p.y;
    }
    if (m == 0){
        float2 i0 = make_float2(0.f, 0.f);
        #pragma unroll 8
        for (int o=0;o<64;++o){
            float2 hv = make_float2(hidr[h*64+o], him[h*64+o]);
            float2 p = cmul(vrow[g][o], hv);
            i0.x += p.x; i0.y += p.y;
        }
        inu[g] = i0;
    }
    float2 a = Aseq[m*HD + hn];
    buf[0][g][m] = make_float4(a.x, a.y, acc.x, acc.y);
    __syncthreads();
    int pb = 0;
    #pragma unroll
    for (int d = 1; d < LSEQ; d <<= 1){
        float4 cur = buf[pb][g][m];
        float4 o2 = cur;
        if (m >= d){
            float4 prev = buf[pb][g][m-d];
            float2 cA = make_float2(cur.x, cur.y), cU = make_float2(cur.z, cur.w);
            float2 pA = make_float2(prev.x, prev.y), pU = make_float2(prev.z, prev.w);
            float2 nA = cmul(cA, pA);
            float2 nU = cmul(cA, pU);
            nU.x += cU.x; nU.y += cU.y;
            o2 = make_float4(nA.x, nA.y, nU.x, nU.y);
        }
        buf[pb^1][g][m] = o2;
        pb ^= 1;
        __syncthreads();
    }
    float4 t = buf[pb][g][m];
    float2 init = inu[g];
    float2 st = cmul(make_float2(t.x, t.y), init);
    st.x += t.z; st.y += t.w;
    Sb[m*DIMN + hn*2]   = f2bf(st.x);
    Sb[m*DIMN + hn*2+1] = f2bf(st.y);
    if (m == LSEQ-1) S255[hn] = st;
}

// ---------- fallback-only kernels ----------
__global__ __launch_bounds__(256) void vmul_kernel(const float* __restrict__ Vr,
                            const float* __restrict__ Vi,
                            const float2* __restrict__ S, ushort* __restrict__ hrb,
                            float* __restrict__ out_tail, int tail_n){
    int g = blockIdx.x*256 + threadIdx.x;
    int m = g >> 9, hn = g & 511;
    int h = hn >> 6;
    const float* vr = &Vr[hn*64];
    const float* vi = &Vi[hn*64];
    const float2* srow = &S[m*HD + h*64];
    float2 acc = make_float2(0.f, 0.f);
    #pragma unroll 8
    for (int o=0;o<64;++o){
        float2 v = make_float2(vr[o], vi[o]);
        float2 p = cmul(v, srow[o]);
        acc.x += p.x; acc.y += p.y;
    }
    hrb[m*DIMN + hn*2]   = f2bf(acc.x);
    hrb[m*DIMN + hn*2+1] = f2bf(acc.y);
    if (m == LSEQ-1){
        if (tail_n >= 1024){
            out_tail[hn]       = acc.x;
            out_tail[512 + hn] = acc.y;
        } else if (tail_n >= 512){
            out_tail[hn] = acc.x;
        }
    }
}

__global__ __launch_bounds__(512) void upscan_f32_kernel(const float2* __restrict__ Vinv,
        const float* __restrict__ hidr, const float* __restrict__ him,
        const float2* __restrict__ XC, const float2* __restrict__ Aseq,
        float2* __restrict__ S){
    __shared__ float4 buf[2][2][LSEQ];
    __shared__ float2 vrow[2][64];
    __shared__ float2 inu[2];
    const int b = blockIdx.x;
    const int tid = threadIdx.x;
    const int g = tid >> 8, m = tid & 255;
    const int hn = b*2 + g;
    const int h = hn >> 6;
    if (m < 64) vrow[g][m] = Vinv[hn*64 + m];
    __syncthreads();
    float2 acc = make_float2(0.f, 0.f);
    const float2* xrow = &XC[m*HD + h*64];
    #pragma unroll 8
    for (int o=0;o<64;++o){
        float2 p = cmul(vrow[g][o], xrow[o]);
        acc.x += p.x; acc.y += p.y;
    }
    if (m == 0){
        float2 i0 = make_float2(0.f, 0.f);
        #pragma unroll 8
        for (int o=0;o<64;++o){
            float2 hv = make_float2(hidr[h*64+o], him[h*64+o]);
            float2 p = cmul(vrow[g][o], hv);
            i0.x += p.x; i0.y += p.y;
        }
        inu[g] = i0;
    }
    float2 a = Aseq[m*HD + hn];
    buf[0][g][m] = make_float4(a.x, a.y, acc.x, acc.y);
    __syncthreads();
    int pb = 0;
    #pragma unroll
    for (int d = 1; d < LSEQ; d <<= 1){
        float4 cur = buf[pb][g][m];
        float4 o2 = cur;
        if (m >= d){
            float4 prev = buf[pb][g][m-d];
            float2 cA = make_float2(cur.x, cur.y), cU = make_float2(cur.z, cur.w);
            float2 pA = make_float2(prev.x, prev.y), pU = make_float2(prev.z, prev.w);
            float2 nA = cmul(cA, pA);
            float2 nU = cmul(cA, pU);
            nU.x += cU.x; nU.y += cU.y;
            o2 = make_float4(nA.x, nA.y, nU.x, nU.y);
        }
        buf[pb^1][g][m] = o2;
        pb ^= 1;
        __syncthreads();
    }
    float4 t = buf[pb][g][m];
    float2 init = inu[g];
    float2 st = cmul(make_float2(t.x, t.y), init);
    st.x += t.z; st.y += t.w;
    S[m*HD + hn] = st;
}

extern "C" void kernel_launch(void* const* d_in, const int* in_sizes, int n_in,
                              void* d_out, int out_size, void* d_ws, size_t ws_size,
                              hipStream_t stream) {
    const float* x      = (const float*)d_in[0];
    const float* hidr   = (const float*)d_in[1];
    const float* hidi   = (const float*)d_in[2];
    const float* w_in1  = (const float*)d_in[3];
    const float* b_in1  = (const float*)d_in[4];
    const float* w_in2  = (const float*)d_in[5];
    const float* b_in2  = (const float*)d_in[6];
    const float* w_out1 = (const float*)d_in[7];
    const float* b_out1 = (const float*)d_in[8];
    const float* w_out2 = (const float*)d_in[9];
    const float* b_out2 = (const float*)d_in[10];
    const float* Vr     = (const float*)d_in[11];
    const float* Vi     = (const float*)d_in[12];
    float* out = (float*)d_out;
    const int tail_n = out_size - LSEQ*DIMN;
    char* ws = (char*)d_ws;

    if (ws_size >= 14946304u){
        // lifetime-aliased layout (identical to R4-green):
        //   Vinv  [0, 256K)            D1->D4
        //   w2t   [256K, 4.25M)        D1->D3
        //   W3bt  [4.25M, 6.25M)       D2(ride)->D5
        //   w4t   [6.25M, 8.25M)       D3(ride)->D6
        //   w1t   [8.25M, 10.25M)      D1->D2   } reused D3+: XC(1M)+Aseq(1M)
        //   x_bf  [10.25M, 10.75M)     D1->D2   } reused D4+: S255(4K)
        //   t1_bf [10.75M, 11.25M)     D2->D3   } reused D4+: Sb
        //   y1_bf [11.25M, 11.75M)     D5->D6
        float2* Vinv  = (float2*)(ws + 0);
        ushort* w2t   = (ushort*)(ws + 262144);
        ushort* W3bt  = (ushort*)(ws + 4456448);
        ushort* w4t   = (ushort*)(ws + 6553600);
        ushort* w1t   = (ushort*)(ws + 8650752);
        float2* XC    = (float2*)(ws + 8650752);
        float2* Aseq  = (float2*)(ws + 9699328);
        ushort* x_bf  = (ushort*)(ws + 10747904);
        float2* S255  = (float2*)(ws + 10747904);
        ushort* t1_bf = (ushort*)(ws + 11272192);
        ushort* y1_bf = (ushort*)(ws + 11796480);
        ushort* Sb    = t1_bf;

        // D1: slim prep (inv + w1t + w2t + x_bf)
        prep_kernel<<<1608, 512, 0, stream>>>(x, w_in1, w_in2, Vr, Vi,
                                              x_bf, w1t, w2t, Vinv);
        // D2: gemm1 + W3eff riders (1024 blocks)
        gemm_ride<1,8,1><<<1280, 512, 0, stream>>>(x_bf, w1t, b_in1, nullptr, t1_bf,
                nullptr, nullptr, LSEQ, DIMN, Vr, Vi, w_out1, W3bt, nullptr, nullptr);
        // D3: gemm2 + w4t riders (512 blocks)
        gemm_ride<2,4,2><<<768, 512, 0, stream>>>(t1_bf, w2t, b_in2, nullptr, nullptr,
                XC, Aseq, LSEQ, 2048, nullptr, nullptr, nullptr, nullptr, w_out2, w4t);
        // D4: upscan
        upscan_kernel<<<256, 512, 0, stream>>>(Vinv, hidr, hidi, XC, Aseq, Sb, S255);
        // D5: gemm3 + hidden_next tail
        gemm_ks<1,8><<<257, 512, 0, stream>>>(Sb, W3bt, b_out1, nullptr, y1_bf,
                nullptr, nullptr, LSEQ, DIMN, Vr, Vi, S255, out + LSEQ*DIMN, tail_n);
        // D6: gemm4
        gemm_ks<0,8><<<256, 512, 0, stream>>>(y1_bf, w4t, b_out2, out, nullptr,
                nullptr, nullptr, LSEQ, DIMN, nullptr, nullptr, nullptr, nullptr, 0);
    } else {
        // ---- R14 fallback: serial prep + full vmul path ----
        float2* Vinv  = (float2*)(ws + 0);
        ushort* wt    = (ushort*)(ws + 262144);
        ushort* x_bf  = (ushort*)(ws + 4456448);
        ushort* t1_bf = (ushort*)(ws + 4980736);
        float2* XC    = (float2*)(ws + 5505024);
        float2* Aseq  = (float2*)(ws + 6553600);
        float2* S     = (float2*)(ws + 7602176);
        ushort* y1_bf = x_bf;
        ushort* hr_bf = t1_bf;

        inv_kernel<<<NH, 512, 0, stream>>>(Vr, Vi, Vinv);
        cvt_bf16_kernel<<<LSEQ*DIMN/4/256, 256, 0, stream>>>(x, x_bf, LSEQ*DIMN/4);
        transpose_cvt<<<dim3(32,32), 256, 0, stream>>>(w_in1, wt, DIMN, DIMN);
        gemm_bt<1><<<dim3(16,4), 256, 0, stream>>>(x_bf, wt, b_in1, nullptr, t1_bf,
                nullptr, nullptr, LSEQ, DIMN, DIMN, nullptr, nullptr, nullptr, nullptr, 0);
        transpose_cvt<<<dim3(64,32), 256, 0, stream>>>(w_in2, wt, DIMN, 2048);
        gemm_bt<2><<<dim3(32,4), 256, 0, stream>>>(t1_bf, wt, b_in2, nullptr, nullptr,
                XC, Aseq, LSEQ, 2048, DIMN, nullptr, nullptr, nullptr, nullptr, 0);
        upscan_f32_kernel<<<256, 512, 0, stream>>>(Vinv, hidr, hidi, XC, Aseq, S);
        vmul_kernel<<<LSEQ*HD/256, 256, 0, stream>>>(Vr, Vi, S, hr_bf, out + LSEQ*DIMN, tail_n);
        transpose_cvt<<<dim3(32,32), 256, 0, stream>>>(w_out1, wt, DIMN, DIMN);
        gemm_bt<1><<<dim3(16,4), 256, 0, stream>>>(hr_bf, wt, b_out1, nullptr, y1_bf,
                nullptr, nullptr, LSEQ, DIMN, DIMN, nullptr, nullptr, nullptr, nullptr, 0);
        transpose_cvt<<<dim3(32,32), 256, 0, stream>>>(w_out2, wt, DIMN, DIMN);
        gemm_bt<0><<<dim3(16,4), 256, 0, stream>>>(y1_bf, wt, b_out2, out, nullptr,
                nullptr, nullptr, LSEQ, DIMN, DIMN, nullptr, nullptr, nullptr, nullptr, 0);
    }
}

// Round 10
// 192.569 us; speedup vs baseline: 1.5038x; 1.0490x over previous
//
#include <hip/hip_runtime.h>
#include <math.h>

#define DIMN 1024
#define NH 8
#define ND 64
#define LSEQ 256
#define HD 512      // NH*ND

typedef __attribute__((ext_vector_type(8))) short short8;
typedef __attribute__((ext_vector_type(4))) float f32x4;

__device__ __forceinline__ float2 cmul(float2 a, float2 b){
    return make_float2(a.x*b.x - a.y*b.y, a.x*b.y + a.y*b.x);
}
__device__ __forceinline__ ushort f2bf(float f){
    union { float f; unsigned u; } v; v.f = f;
    unsigned r = v.u + 0x7FFF + ((v.u >> 16) & 1);   // RNE
    return (ushort)(r >> 16);
}

#define ISTR 65
#define ASTR 40
#define BK 32

// ---------- blocked (NB=8) in-place Gauss-Jordan (R11/R14-verified, verbatim) ----------
__device__ __forceinline__ void inv_gj_blocked(const float* __restrict__ Vr,
        const float* __restrict__ Vi, float2* __restrict__ Vinv,
        int h, int tid, float2* Mx){
    for (int idx = tid; idx < 4096; idx += 512){
        int i = idx >> 6, j = idx & 63;
        Mx[i*ISTR + j] = make_float2(Vr[h*4096 + idx], Vi[h*4096 + idx]);
    }
    __syncthreads();
    const int w = tid >> 6, l = tid & 63;
    const int rbase = w*8;
    for (int kb = 0; kb < 8; ++kb){
        const int k0 = kb*8;
        if (w == 0){
            float2 pr[8];
            #pragma unroll
            for (int m = 0; m < 8; ++m) pr[m] = Mx[l*ISTR + k0 + m];
            #pragma unroll
            for (int k = 0; k < 8; ++k){
                const int gk = k0 + k;
                float2 d; d.x = __shfl(pr[k].x, gk); d.y = __shfl(pr[k].y, gk);
                float im = 1.f/(d.x*d.x + d.y*d.y);
                float2 p = make_float2(d.x*im, -d.y*im);
                float2 spr[8];
                #pragma unroll
                for (int m = 0; m < 8; ++m){
                    float2 t; t.x = __shfl(pr[m].x, gk); t.y = __shfl(pr[m].y, gk);
                    spr[m] = (m == k) ? p : cmul(t, p);
                }
                float2 f = pr[k];
                if (l == gk){
                    #pragma unroll
                    for (int m = 0; m < 8; ++m) pr[m] = spr[m];
                } else {
                    #pragma unroll
                    for (int m = 0; m < 8; ++m){
                        float2 u = cmul(f, spr[m]);
                        if (m == k){ pr[m].x = -u.x;  pr[m].y = -u.y;  }
                        else       { pr[m].x -= u.x;  pr[m].y -= u.y;  }
                    }
                }
            }
            #pragma unroll
            for (int m = 0; m < 8; ++m) Mx[l*ISTR + k0 + m] = pr[m];
        }
        __syncthreads();
        float2 br[8];
        #pragma unroll
        for (int m = 0; m < 8; ++m) br[m] = Mx[(k0+m)*ISTR + l];
        __syncthreads();
        if (((unsigned)(l - k0)) >= 8u){
            #pragma unroll
            for (int rr = 0; rr < 8; ++rr){
                const int r = rbase + rr;
                float2 acc;
                if (((unsigned)(r - k0)) < 8u){ acc.x = 0.f; acc.y = 0.f; }
                else acc = Mx[r*ISTR + l];
                #pragma unroll
                for (int m = 0; m < 8; ++m){
                    float2 Pv = Mx[r*ISTR + k0 + m];
                    acc.x += Pv.x*br[m].x - Pv.y*br[m].y;
                    acc.y += Pv.x*br[m].y + Pv.y*br[m].x;
                }
                Mx[r*ISTR + l] = acc;
            }
        }
        __syncthreads();
    }
    for (int idx = tid; idx < 4096; idx += 512){
        int i = idx >> 6, j = idx & 63;
        Vinv[h*4096 + idx] = Mx[i*ISTR + j];
    }
}

// ---------- W3eff tile (R16-verified): fold V into w_out1 ----------
__device__ __forceinline__ void w3eff_tile(const float* __restrict__ Vr,
        const float* __restrict__ Vi, const float* __restrict__ w3,
        ushort* __restrict__ W3bt, int t, int tid, float* lds){
    const int n0 = (t & 31)*32;
    const int c0 = (t >> 5)*32;
    const int h  = c0 >> 7;
    const int og0 = (c0 & 127) >> 1;
    float* Vbr = lds;            // 64 x 16
    float* Vbi = lds + 1024;     // 64 x 16
    float* Wb  = lds + 2048;     // 128 x 32
    for (int q = tid; q < 1024; q += 512){
        int dd = q >> 4, oo = q & 15;
        Vbr[q] = Vr[(h*64+dd)*64 + og0 + oo];
        Vbi[q] = Vi[(h*64+dd)*64 + og0 + oo];
    }
    for (int q = tid; q < 4096; q += 512){
        int row = q >> 5, nn = q & 31;
        Wb[q] = w3[(h*128 + row)*1024 + n0 + nn];
    }
    __syncthreads();
    const int nn = tid & 31, oo = tid >> 5;    // oo 0..15
    float ar = 0.f, ai = 0.f;
    #pragma unroll 8
    for (int dd = 0; dd < 64; ++dd){
        float vr = Vbr[dd*16 + oo], vi = Vbi[dd*16 + oo];
        float w0 = Wb[(dd*2)*32 + nn], w1v = Wb[(dd*2+1)*32 + nn];
        ar += vr*w0 + vi*w1v;
        ai += -vi*w0 + vr*w1v;
    }
    W3bt[(n0+nn)*1024 + c0 + oo*2 + 0] = f2bf(ar);
    W3bt[(n0+nn)*1024 + c0 + oo*2 + 1] = f2bf(ai);
}

// ---------- prep (pure): w1t + w2t + x->bf16 (no inv, no W3eff, no w4t) ----------
// blocks [0,512): w1t; [512,1536): w2t; [1536,1600): x cvt.
__global__ __launch_bounds__(512) void prep_kernel(
        const float* __restrict__ x,
        const float* __restrict__ w1, const float* __restrict__ w2,
        ushort* __restrict__ x_bf,
        ushort* __restrict__ w1t, ushort* __restrict__ w2t){
    __shared__ __align__(16) char lds_raw[33280];
    const int b = blockIdx.x;
    const int tid = threadIdx.x;
    const int half = tid >> 8;

    int u = b;
    if (u < 1536){
        const float* W; ushort* Wt; const int K = 1024; int N; int t;
        if (u < 512){ W = w1; Wt = w1t; N = 1024; t = u*2 + half; }
        else        { W = w2; Wt = w2t; N = 2048; t = (u-512)*2 + half; }
        const int tiles_n = N >> 5;
        const int n0 = (t % tiles_n) * 32, k0 = (t / tiles_n) * 32;
        float* tile = (float*)lds_raw + half*(32*33);
        const int tx = tid & 31, ty = (tid >> 5) & 7;
        #pragma unroll
        for (int i = 0; i < 4; ++i)
            tile[(ty + i*8)*33 + tx] = W[(k0 + ty + i*8)*N + n0 + tx];
        __syncthreads();
        #pragma unroll
        for (int i = 0; i < 4; ++i){
            int r = ty + i*8;
            Wt[(n0 + r)*K + k0 + tx] = f2bf(tile[tx*33 + r]);
        }
        return;
    }
    u -= 1536;
    // u < 64: x -> bf16, 64 blocks * 512 thr * 2 float4
    const int base = (u*512 + tid)*2;
    #pragma unroll
    for (int j = 0; j < 2; ++j){
        float4 v = ((const float4*)x)[base + j];
        ushort4 uu; uu.x=f2bf(v.x); uu.y=f2bf(v.y); uu.z=f2bf(v.z); uu.w=f2bf(v.w);
        ((ushort4*)x_bf)[base + j] = uu;
    }
}

// ---------- K-split GEMM phase (verbatim R4-verified) ----------
template<int ACT, int KS>
__device__ __forceinline__ void gemm_phase(const ushort* __restrict__ A,
        const ushort* __restrict__ Bt, const float* __restrict__ bias,
        float* __restrict__ Cf, ushort* __restrict__ Cb,
        float2* __restrict__ XCo, float2* __restrict__ Ao,
        int M, int N, int blk, int tid, float* red){
    constexpr int Kw = 1024/KS;
    constexpr int TPBT = 8/KS;
    const int wave = tid >> 6, l = tid & 63;
    const int ml = l & 15, quad = l >> 4;
    const int lt = wave / KS, ks = wave - lt*KS;
    const int tile = blk*TPBT + lt;
    const int tm = M >> 5;
    const int bm = (tile % tm)*32, bn = (tile / tm)*32;
    const ushort* Ap = A  + (bm + ml)*1024 + ks*Kw + quad*8;
    const ushort* Bp = Bt + (bn + ml)*1024 + ks*Kw + quad*8;

    f32x4 acc[2][2];
    #pragma unroll
    for (int i=0;i<2;++i)
        #pragma unroll
        for (int j=0;j<2;++j) acc[i][j] = (f32x4){0.f,0.f,0.f,0.f};

    short8 ac[2], bc[2];
    ac[0] = *(const short8*)(Ap);
    ac[1] = *(const short8*)(Ap + 16*1024);
    bc[0] = *(const short8*)(Bp);
    bc[1] = *(const short8*)(Bp + 16*1024);

    #pragma unroll
    for (int k0 = 32; k0 < Kw; k0 += 32){
        short8 an[2], bn2[2];
        an[0]  = *(const short8*)(Ap + k0);
        an[1]  = *(const short8*)(Ap + 16*1024 + k0);
        bn2[0] = *(const short8*)(Bp + k0);
        bn2[1] = *(const short8*)(Bp + 16*1024 + k0);
        #pragma unroll
        for (int i=0;i<2;++i)
            #pragma unroll
            for (int j=0;j<2;++j)
                acc[i][j] = __builtin_amdgcn_mfma_f32_16x16x32_bf16(ac[i], bc[j], acc[i][j], 0,0,0);
        ac[0]=an[0]; ac[1]=an[1]; bc[0]=bn2[0]; bc[1]=bn2[1];
    }
    #pragma unroll
    for (int i=0;i<2;++i)
        #pragma unroll
        for (int j=0;j<2;++j)
            acc[i][j] = __builtin_amdgcn_mfma_f32_16x16x32_bf16(ac[i], bc[j], acc[i][j], 0,0,0);

    // partial-sum reduction: red[wave][16][64]
    #pragma unroll
    for (int i=0;i<2;++i)
        #pragma unroll
        for (int j=0;j<2;++j)
            #pragma unroll
            for (int r=0;r<4;++r)
                red[wave*1024 + ((i*2+j)*4+r)*64 + l] = acc[i][j][r];
    __syncthreads();

    if (ks == 0){
        #pragma unroll
        for (int i=0;i<2;++i){
            #pragma unroll
            for (int j=0;j<2;++j){
                const int gcol = bn + j*16 + ml;
                const float bsv = bias[gcol];
                #pragma unroll
                for (int r=0;r<4;++r){
                    float val = bsv;
                    #pragma unroll
                    for (int s=0;s<KS;++s)
                        val += red[(wave+s)*1024 + ((i*2+j)*4+r)*64 + l];
                    const int grow = bm + i*16 + quad*4 + r;
                    if (ACT == 2){
                        float v1 = __shfl_down(val, 1);
                        float v2 = __shfl_down(val, 2);
                        float v3 = __shfl_down(val, 3);
                        if ((l & 3) == 0){
                            int hd = gcol >> 2;
                            XCo[grow*HD + hd] = make_float2(val, v1);
                            float m2 = v2*v2 + v3*v3;
                            float s = sqrtf(m2)/(1.f + m2);
                            Ao[grow*HD + hd] = make_float2(v2*s, v3*s);
                        }
                    } else if (ACT == 1){
                        val *= 1.f/(1.f + expf(-val));
                        Cb[grow*N + gcol] = f2bf(val);
                    } else {
                        Cf[grow*N + gcol] = val;
                    }
                }
            }
        }
    }
}

// ---------- D2: inv (blocks 0-7, scheduled first) + gemm1 (8..264) + W3eff riders ----------
__global__ __launch_bounds__(512) void gemm1_inv_w3(const ushort* __restrict__ A,
        const ushort* __restrict__ Bt, const float* __restrict__ bias,
        ushort* __restrict__ Cb,
        const float* __restrict__ Vr, const float* __restrict__ Vi,
        float2* __restrict__ Vinv,
        const float* __restrict__ w3, ushort* __restrict__ W3bt){
    __shared__ __align__(16) char lds_raw[33280];
    const int b = blockIdx.x;
    if (b < 8){
        inv_gj_blocked(Vr, Vi, Vinv, b, threadIdx.x, (float2*)lds_raw);
        return;
    }
    if (b < 264){
        gemm_phase<1,8>(A, Bt, bias, nullptr, Cb, nullptr, nullptr,
                        256, 1024, b - 8, threadIdx.x, (float*)lds_raw);
        return;
    }
    w3eff_tile(Vr, Vi, w3, W3bt, b - 264, threadIdx.x, (float*)lds_raw);
}

// ---------- D3: gemm2 + w4t riders (verbatim R9 gemm_ride<2,4,2>) ----------
__global__ __launch_bounds__(512) void gemm2_w4(const ushort* __restrict__ A,
        const ushort* __restrict__ Bt, const float* __restrict__ bias,
        float2* __restrict__ XCo, float2* __restrict__ Ao,
        const float* __restrict__ w4, ushort* __restrict__ w4t){
    __shared__ __align__(16) char lds_raw[33280];
    const int ntb = 256;
    if ((int)blockIdx.x >= ntb){
        const int u = (int)blockIdx.x - ntb;
        const int tid = threadIdx.x;
        const int half = tid >> 8;
        const int t = u*2 + half;
        const int n0 = (t & 31)*32, k0 = (t >> 5)*32;
        float* tile = (float*)lds_raw + half*(32*33);
        const int tx = tid & 31, ty = (tid >> 5) & 7;
        #pragma unroll
        for (int i = 0; i < 4; ++i)
            tile[(ty + i*8)*33 + tx] = w4[(k0 + ty + i*8)*1024 + n0 + tx];
        __syncthreads();
        #pragma unroll
        for (int i = 0; i < 4; ++i){
            int r = ty + i*8;
            w4t[(n0 + r)*1024 + k0 + tx] = f2bf(tile[tx*33 + r]);
        }
        return;
    }
    gemm_phase<2,4>(A, Bt, bias, nullptr, nullptr, XCo, Ao,
                    256, 2048, blockIdx.x, threadIdx.x, (float*)lds_raw);
}

// ---------- standalone K-split GEMM dispatch (verbatim R4). Tail block
// computes the hidden_next tail (gemm3 only, out_tail != nullptr). ----------
template<int ACT, int KS>
__global__ __launch_bounds__(512) void gemm_ks(const ushort* __restrict__ A,
        const ushort* __restrict__ Bt, const float* __restrict__ bias,
        float* __restrict__ Cf, ushort* __restrict__ Cb,
        float2* __restrict__ XCo, float2* __restrict__ Ao,
        int M, int N,
        const float* __restrict__ tVr, const float* __restrict__ tVi,
        const float2* __restrict__ S255, float* __restrict__ out_tail,
        int tail_n){
    __shared__ float red[8*1024];
    const int nt = (M >> 5) * (N >> 5);
    const int ntb = nt / (8/KS);
    if (out_tail != nullptr && blockIdx.x >= ntb){
        if ((threadIdx.x >> 6) == 0 && tail_n >= 512){
            const int l = threadIdx.x & 63;
            for (int hn = l; hn < 512; hn += 64){
                const int h = hn >> 6;
                float2 acc2 = make_float2(0.f, 0.f);
                #pragma unroll 8
                for (int o = 0; o < 64; ++o){
                    float2 v = make_float2(tVr[hn*64+o], tVi[hn*64+o]);
                    float2 p = cmul(v, S255[h*64+o]);
                    acc2.x += p.x; acc2.y += p.y;
                }
                if (tail_n >= 1024){
                    out_tail[hn]       = acc2.x;
                    out_tail[512 + hn] = acc2.y;
                } else {
                    out_tail[hn] = acc2.x;
                }
            }
        }
        return;
    }
    gemm_phase<ACT, KS>(A, Bt, bias, Cf, Cb, XCo, Ao, M, N,
                        blockIdx.x, threadIdx.x, red);
}

// ---------- serial-fallback kernels (R14 path; used only if ws too small) ----------
__global__ __launch_bounds__(512) void inv_kernel(const float* __restrict__ Vr,
                                                  const float* __restrict__ Vi,
                                                  float2* __restrict__ Vinv){
    __shared__ float2 Mx[64*ISTR];
    inv_gj_blocked(Vr, Vi, Vinv, blockIdx.x, threadIdx.x, Mx);
}

__global__ __launch_bounds__(256) void transpose_cvt(const float* __restrict__ W,
                 ushort* __restrict__ Wt, int K, int N){
    __shared__ float tile[32][33];
    const int n0 = blockIdx.x * 32, k0 = blockIdx.y * 32;
    const int tx = threadIdx.x & 31, ty = threadIdx.x >> 5;
    #pragma unroll
    for (int i = 0; i < 4; ++i)
        tile[ty + i*8][tx] = W[(k0 + ty + i*8)*N + n0 + tx];
    __syncthreads();
    #pragma unroll
    for (int i = 0; i < 4; ++i){
        int r = ty + i*8;
        Wt[(n0 + r)*K + k0 + tx] = f2bf(tile[tx][r]);
    }
}

__global__ __launch_bounds__(256) void cvt_bf16_kernel(const float* __restrict__ in,
                                 ushort* __restrict__ o, int n4){
    int i = blockIdx.x*256 + threadIdx.x;
    if (i < n4){
        float4 v = ((const float4*)in)[i];
        ushort4 u; u.x=f2bf(v.x); u.y=f2bf(v.y); u.z=f2bf(v.z); u.w=f2bf(v.w);
        ((ushort4*)o)[i] = u;
    }
}

// ---------- bf16 MFMA GEMM, 64x64 tile (R14-verified). Fallback path only. ----------
#define BM 64
#define BN 64
template<int ACT>
__global__ __launch_bounds__(256) void gemm_bt(const ushort* __restrict__ A,
                 const ushort* __restrict__ Bt, const float* __restrict__ bias,
                 float* __restrict__ Cf, ushort* __restrict__ Cb,
                 float2* __restrict__ XCo, float2* __restrict__ Ao,
                 int M, int N, int K,
                 const float* __restrict__ tVr, const float* __restrict__ tVi,
                 const float2* __restrict__ S255, float* __restrict__ out_tail,
                 int tail_n){
    __shared__ ushort As[BM*ASTR];
    __shared__ ushort Bs[BN*ASTR];
    const int tid = threadIdx.x;
    const int bm = blockIdx.y * BM, bn = blockIdx.x * BN;
    const int wave = tid >> 6, l = tid & 63;
    const int wr = (wave >> 1) * 32, wc = (wave & 1) * 32;
    const int ml = l & 15, quad = l >> 4;

    if (ACT == 0 && out_tail != nullptr && blockIdx.x == 0 && blockIdx.y == 0){
        for (int hn = tid; hn < 512; hn += 256){
            int h = hn >> 6;
            float2 acc2 = make_float2(0.f, 0.f);
            #pragma unroll 8
            for (int o = 0; o < 64; ++o){
                float2 v = make_float2(tVr[hn*64+o], tVi[hn*64+o]);
                float2 p = cmul(v, S255[h*64+o]);
                acc2.x += p.x; acc2.y += p.y;
            }
            if (tail_n >= 1024){
                out_tail[hn]       = acc2.x;
                out_tail[512 + hn] = acc2.y;
            } else if (tail_n >= 512){
                out_tail[hn] = acc2.x;
            }
        }
    }

    f32x4 acc[2][2];
    #pragma unroll
    for (int i=0;i<2;++i)
        #pragma unroll
        for (int j=0;j<2;++j) acc[i][j] = (f32x4){0.f,0.f,0.f,0.f};
    const int c0r = tid >> 2;
    const int c0s = tid & 3;
    for (int k0 = 0; k0 < K; k0 += BK){
        uint4 av = *(const uint4*)&A [(bm + c0r)*K + k0 + c0s*8];
        uint4 bv = *(const uint4*)&Bt[(bn + c0r)*K + k0 + c0s*8];
        __syncthreads();
        *(uint4*)&As[c0r*ASTR + c0s*8] = av;
        *(uint4*)&Bs[c0r*ASTR + c0s*8] = bv;
        __syncthreads();
        short8 af[2], bfv[2];
        #pragma unroll
        for (int f=0; f<2; ++f){
            af[f]  = *(const short8*)&As[(wr + f*16 + ml)*ASTR + quad*8];
            bfv[f] = *(const short8*)&Bs[(wc + f*16 + ml)*ASTR + quad*8];
        }
        #pragma unroll
        for (int i=0;i<2;++i)
            #pragma unroll
            for (int j=0;j<2;++j)
                acc[i][j] = __builtin_amdgcn_mfma_f32_16x16x32_bf16(af[i], bfv[j], acc[i][j], 0,0,0);
    }
    #pragma unroll
    for (int i=0;i<2;++i){
        #pragma unroll
        for (int j=0;j<2;++j){
            const int gcol = bn + wc + j*16 + ml;
            const float bsv = bias[gcol];
            #pragma unroll
            for (int r=0;r<4;++r){
                const int grow = bm + wr + i*16 + quad*4 + r;
                float val = acc[i][j][r] + bsv;
                if (ACT == 2){
                    float v1 = __shfl_down(val, 1);
                    float v2 = __shfl_down(val, 2);
                    float v3 = __shfl_down(val, 3);
                    if ((l & 3) == 0){
                        int hd = gcol >> 2;
                        XCo[grow*HD + hd] = make_float2(val, v1);
                        float m2 = v2*v2 + v3*v3;
                        float s = sqrtf(m2)/(1.f + m2);
                        Ao[grow*HD + hd] = make_float2(v2*s, v3*s);
                    }
                } else if (ACT == 1){
                    val *= 1.f/(1.f + expf(-val));
                    Cb[grow*N + gcol] = f2bf(val);
                } else {
                    Cf[grow*N + gcol] = val;
                }
            }
        }
    }
}

// ---------- fused uext + parallel scan; writes Sb (bf16, hr-layout) + S255 fp32 ----------
__global__ __launch_bounds__(512) void upscan_kernel(const float2* __restrict__ Vinv,
        const float* __restrict__ hidr, const float* __restrict__ him,
        const float2* __restrict__ XC, const float2* __restrict__ Aseq,
        ushort* __restrict__ Sb, float2* __restrict__ S255){
    __shared__ float4 buf[2][2][LSEQ];
    __shared__ float2 vrow[2][64];
    __shared__ float2 inu[2];
    const int b = blockIdx.x;
    const int tid = threadIdx.x;
    const int g = tid >> 8, m = tid & 255;
    const int hn = b*2 + g;
    const int h = hn >> 6;
    if (m < 64) vrow[g][m] = Vinv[hn*64 + m];
    __syncthreads();
    float2 acc = make_float2(0.f, 0.f);
    const float2* xrow = &XC[m*HD + h*64];
    #pragma unroll 8
    for (int o=0;o<64;++o){
        float2 p = cmul(vrow[g][o], xrow[o]);
        acc.x += p.x; acc.y += p.y;
    }
    if (m == 0){
        float2 i0 = make_float2(0.f, 0.f);
        #pragma unroll 8
        for (int o=0;o<64;++o){
            float2 hv = make_float2(hidr[h*64+o], him[h*64+o]);
            float2 p = cmul(vrow[g][o], hv);
            i0.x += p.x; i0.y += p.y;
        }
        inu[g] = i0;
    }
    float2 a = Aseq[m*HD + hn];
    buf[0][g][m] = make_float4(a.x, a.y, acc.x, acc.y);
    __syncthreads();
    int pb = 0;
    #pragma unroll
    for (int d = 1; d < LSEQ; d <<= 1){
        float4 cur = buf[pb][g][m];
        float4 o2 = cur;
        if (m >= d){
            float4 prev = buf[pb][g][m-d];
            float2 cA = make_float2(cur.x, cur.y), cU = make_float2(cur.z, cur.w);
            float2 pA = make_float2(prev.x, prev.y), pU = make_float2(prev.z, prev.w);
            float2 nA = cmul(cA, pA);
            float2 nU = cmul(cA, pU);
            nU.x += cU.x; nU.y += cU.y;
            o2 = make_float4(nA.x, nA.y, nU.x, nU.y);
        }
        buf[pb^1][g][m] = o2;
        pb ^= 1;
        __syncthreads();
    }
    float4 t = buf[pb][g][m];
    float2 init = inu[g];
    float2 st = cmul(make_float2(t.x, t.y), init);
    st.x += t.z; st.y += t.w;
    Sb[m*DIMN + hn*2]   = f2bf(st.x);
    Sb[m*DIMN + hn*2+1] = f2bf(st.y);
    if (m == LSEQ-1) S255[hn] = st;
}

// ---------- fallback-only kernels ----------
__global__ __launch_bounds__(256) void vmul_kernel(const float* __restrict__ Vr,
                            const float* __restrict__ Vi,
                            const float2* __restrict__ S, ushort* __restrict__ hrb,
                            float* __restrict__ out_tail, int tail_n){
    int g = blockIdx.x*256 + threadIdx.x;
    int m = g >> 9, hn = g & 511;
    int h = hn >> 6;
    const float* vr = &Vr[hn*64];
    const float* vi = &Vi[hn*64];
    const float2* srow = &S[m*HD + h*64];
    float2 acc = make_float2(0.f, 0.f);
    #pragma unroll 8
    for (int o=0;o<64;++o){
        float2 v = make_float2(vr[o], vi[o]);
        float2 p = cmul(v, srow[o]);
        acc.x += p.x; acc.y += p.y;
    }
    hrb[m*DIMN + hn*2]   = f2bf(acc.x);
    hrb[m*DIMN + hn*2+1] = f2bf(acc.y);
    if (m == LSEQ-1){
        if (tail_n >= 1024){
            out_tail[hn]       = acc.x;
            out_tail[512 + hn] = acc.y;
        } else if (tail_n >= 512){
            out_tail[hn] = acc.x;
        }
    }
}

__global__ __launch_bounds__(512) void upscan_f32_kernel(const float2* __restrict__ Vinv,
        const float* __restrict__ hidr, const float* __restrict__ him,
        const float2* __restrict__ XC, const float2* __restrict__ Aseq,
        float2* __restrict__ S){
    __shared__ float4 buf[2][2][LSEQ];
    __shared__ float2 vrow[2][64];
    __shared__ float2 inu[2];
    const int b = blockIdx.x;
    const int tid = threadIdx.x;
    const int g = tid >> 8, m = tid & 255;
    const int hn = b*2 + g;
    const int h = hn >> 6;
    if (m < 64) vrow[g][m] = Vinv[hn*64 + m];
    __syncthreads();
    float2 acc = make_float2(0.f, 0.f);
    const float2* xrow = &XC[m*HD + h*64];
    #pragma unroll 8
    for (int o=0;o<64;++o){
        float2 p = cmul(vrow[g][o], xrow[o]);
        acc.x += p.x; acc.y += p.y;
    }
    if (m == 0){
        float2 i0 = make_float2(0.f, 0.f);
        #pragma unroll 8
        for (int o=0;o<64;++o){
            float2 hv = make_float2(hidr[h*64+o], him[h*64+o]);
            float2 p = cmul(vrow[g][o], hv);
            i0.x += p.x; i0.y += p.y;
        }
        inu[g] = i0;
    }
    float2 a = Aseq[m*HD + hn];
    buf[0][g][m] = make_float4(a.x, a.y, acc.x, acc.y);
    __syncthreads();
    int pb = 0;
    #pragma unroll
    for (int d = 1; d < LSEQ; d <<= 1){
        float4 cur = buf[pb][g][m];
        float4 o2 = cur;
        if (m >= d){
            float4 prev = buf[pb][g][m-d];
            float2 cA = make_float2(cur.x, cur.y), cU = make_float2(cur.z, cur.w);
            float2 pA = make_float2(prev.x, prev.y), pU = make_float2(prev.z, prev.w);
            float2 nA = cmul(cA, pA);
            float2 nU = cmul(cA, pU);
            nU.x += cU.x; nU.y += cU.y;
            o2 = make_float4(nA.x, nA.y, nU.x, nU.y);
        }
        buf[pb^1][g][m] = o2;
        pb ^= 1;
        __syncthreads();
    }
    float4 t = buf[pb][g][m];
    float2 init = inu[g];
    float2 st = cmul(make_float2(t.x, t.y), init);
    st.x += t.z; st.y += t.w;
    S[m*HD + hn] = st;
}

extern "C" void kernel_launch(void* const* d_in, const int* in_sizes, int n_in,
                              void* d_out, int out_size, void* d_ws, size_t ws_size,
                              hipStream_t stream) {
    const float* x      = (const float*)d_in[0];
    const float* hidr   = (const float*)d_in[1];
    const float* hidi   = (const float*)d_in[2];
    const float* w_in1  = (const float*)d_in[3];
    const float* b_in1  = (const float*)d_in[4];
    const float* w_in2  = (const float*)d_in[5];
    const float* b_in2  = (const float*)d_in[6];
    const float* w_out1 = (const float*)d_in[7];
    const float* b_out1 = (const float*)d_in[8];
    const float* w_out2 = (const float*)d_in[9];
    const float* b_out2 = (const float*)d_in[10];
    const float* Vr     = (const float*)d_in[11];
    const float* Vi     = (const float*)d_in[12];
    float* out = (float*)d_out;
    const int tail_n = out_size - LSEQ*DIMN;
    char* ws = (char*)d_ws;

    if (ws_size >= 14946304u){
        // lifetime-aliased layout (identical to R4/R9-green):
        //   Vinv  [0, 256K)            D2(inv)->D4
        //   w2t   [256K, 4.25M)        D1->D3
        //   W3bt  [4.25M, 6.25M)       D2(ride)->D5
        //   w4t   [6.25M, 8.25M)       D3(ride)->D6
        //   w1t   [8.25M, 10.25M)      D1->D2   } reused D3+: XC(1M)+Aseq(1M)
        //   x_bf  [10.25M, 10.75M)     D1->D2   } reused D4+: S255(4K)
        //   t1_bf [10.75M, 11.25M)     D2->D3   } reused D4+: Sb
        //   y1_bf [11.25M, 11.75M)     D5->D6
        float2* Vinv  = (float2*)(ws + 0);
        ushort* w2t   = (ushort*)(ws + 262144);
        ushort* W3bt  = (ushort*)(ws + 4456448);
        ushort* w4t   = (ushort*)(ws + 6553600);
        ushort* w1t   = (ushort*)(ws + 8650752);
        float2* XC    = (float2*)(ws + 8650752);
        float2* Aseq  = (float2*)(ws + 9699328);
        ushort* x_bf  = (ushort*)(ws + 10747904);
        float2* S255  = (float2*)(ws + 10747904);
        ushort* t1_bf = (ushort*)(ws + 11272192);
        ushort* y1_bf = (ushort*)(ws + 11796480);
        ushort* Sb    = t1_bf;

        // D1: pure prep (w1t + w2t + x_bf) — no inv
        prep_kernel<<<1600, 512, 0, stream>>>(x, w_in1, w_in2, x_bf, w1t, w2t);
        // D2: inv (blocks 0-7, first) + gemm1 (256) + W3eff riders (1024)
        gemm1_inv_w3<<<1288, 512, 0, stream>>>(x_bf, w1t, b_in1, t1_bf,
                Vr, Vi, Vinv, w_out1, W3bt);
        // D3: gemm2 (256) + w4t riders (512)
        gemm2_w4<<<768, 512, 0, stream>>>(t1_bf, w2t, b_in2, XC, Aseq, w_out2, w4t);
        // D4: upscan
        upscan_kernel<<<256, 512, 0, stream>>>(Vinv, hidr, hidi, XC, Aseq, Sb, S255);
        // D5: gemm3 + hidden_next tail
        gemm_ks<1,8><<<257, 512, 0, stream>>>(Sb, W3bt, b_out1, nullptr, y1_bf,
                nullptr, nullptr, LSEQ, DIMN, Vr, Vi, S255, out + LSEQ*DIMN, tail_n);
        // D6: gemm4
        gemm_ks<0,8><<<256, 512, 0, stream>>>(y1_bf, w4t, b_out2, out, nullptr,
                nullptr, nullptr, LSEQ, DIMN, nullptr, nullptr, nullptr, nullptr, 0);
    } else {
        // ---- R14 fallback: serial prep + full vmul path ----
        float2* Vinv  = (float2*)(ws + 0);
        ushort* wt    = (ushort*)(ws + 262144);
        ushort* x_bf  = (ushort*)(ws + 4456448);
        ushort* t1_bf = (ushort*)(ws + 4980736);
        float2* XC    = (float2*)(ws + 5505024);
        float2* Aseq  = (float2*)(ws + 6553600);
        float2* S     = (float2*)(ws + 7602176);
        ushort* y1_bf = x_bf;
        ushort* hr_bf = t1_bf;

        inv_kernel<<<NH, 512, 0, stream>>>(Vr, Vi, Vinv);
        cvt_bf16_kernel<<<LSEQ*DIMN/4/256, 256, 0, stream>>>(x, x_bf, LSEQ*DIMN/4);
        transpose_cvt<<<dim3(32,32), 256, 0, stream>>>(w_in1, wt, DIMN, DIMN);
        gemm_bt<1><<<dim3(16,4), 256, 0, stream>>>(x_bf, wt, b_in1, nullptr, t1_bf,
                nullptr, nullptr, LSEQ, DIMN, DIMN, nullptr, nullptr, nullptr, nullptr, 0);
        transpose_cvt<<<dim3(64,32), 256, 0, stream>>>(w_in2, wt, DIMN, 2048);
        gemm_bt<2><<<dim3(32,4), 256, 0, stream>>>(t1_bf, wt, b_in2, nullptr, nullptr,
                XC, Aseq, LSEQ, 2048, DIMN, nullptr, nullptr, nullptr, nullptr, 0);
        upscan_f32_kernel<<<256, 512, 0, stream>>>(Vinv, hidr, hidi, XC, Aseq, S);
        vmul_kernel<<<LSEQ*HD/256, 256, 0, stream>>>(Vr, Vi, S, hr_bf, out + LSEQ*DIMN, tail_n);
        transpose_cvt<<<dim3(32,32), 256, 0, stream>>>(w_out1, wt, DIMN, DIMN);
        gemm_bt<1><<<dim3(16,4), 256, 0, stream>>>(hr_bf, wt, b_out1, nullptr, y1_bf,
                nullptr, nullptr, LSEQ, DIMN, DIMN, nullptr, nullptr, nullptr, nullptr, 0);
        transpose_cvt<<<dim3(32,32), 256, 0, stream>>>(w_out2, wt, DIMN, DIMN);
        gemm_bt<0><<<dim3(16,4), 256, 0, stream>>>(y1_bf, wt, b_out2, out, nullptr,
                nullptr, nullptr, LSEQ, DIMN, DIMN, nullptr, nullptr, nullptr, nullptr, 0);
    }
}

// Round 11
// 192.282 us; speedup vs baseline: 1.5061x; 1.0015x over previous
//
#include <hip/hip_runtime.h>
#include <math.h>

#define DIMN 1024
#define NH 8
#define ND 64
#define LSEQ 256
#define HD 512      // NH*ND

typedef __attribute__((ext_vector_type(8))) short short8;
typedef __attribute__((ext_vector_type(4))) float f32x4;

__device__ __forceinline__ float2 cmul(float2 a, float2 b){
    return make_float2(a.x*b.x - a.y*b.y, a.x*b.y + a.y*b.x);
}
__device__ __forceinline__ ushort f2bf(float f){
    union { float f; unsigned u; } v; v.f = f;
    unsigned r = v.u + 0x7FFF + ((v.u >> 16) & 1);   // RNE
    return (ushort)(r >> 16);
}

#define ISTR 65
#define ASTR 40
#define BK 32

// ---------- blocked (NB=8) in-place Gauss-Jordan (R11/R14-verified body).
// R11 change: setprio(1) for the duration of the serial chain — the inv is
// latency/issue-bound and loses SIMD issue slots to co-resident gemm waves
// (R9: 42us alone vs R10: 60us co-resident). Priority is a hint; correctness
// unaffected. ----------
__device__ __forceinline__ void inv_gj_blocked(const float* __restrict__ Vr,
        const float* __restrict__ Vi, float2* __restrict__ Vinv,
        int h, int tid, float2* Mx){
    __builtin_amdgcn_s_setprio(1);
    for (int idx = tid; idx < 4096; idx += 512){
        int i = idx >> 6, j = idx & 63;
        Mx[i*ISTR + j] = make_float2(Vr[h*4096 + idx], Vi[h*4096 + idx]);
    }
    __syncthreads();
    const int w = tid >> 6, l = tid & 63;
    const int rbase = w*8;
    for (int kb = 0; kb < 8; ++kb){
        const int k0 = kb*8;
        if (w == 0){
            float2 pr[8];
            #pragma unroll
            for (int m = 0; m < 8; ++m) pr[m] = Mx[l*ISTR + k0 + m];
            #pragma unroll
            for (int k = 0; k < 8; ++k){
                const int gk = k0 + k;
                float2 d; d.x = __shfl(pr[k].x, gk); d.y = __shfl(pr[k].y, gk);
                float im = 1.f/(d.x*d.x + d.y*d.y);
                float2 p = make_float2(d.x*im, -d.y*im);
                float2 spr[8];
                #pragma unroll
                for (int m = 0; m < 8; ++m){
                    float2 t; t.x = __shfl(pr[m].x, gk); t.y = __shfl(pr[m].y, gk);
                    spr[m] = (m == k) ? p : cmul(t, p);
                }
                float2 f = pr[k];
                if (l == gk){
                    #pragma unroll
                    for (int m = 0; m < 8; ++m) pr[m] = spr[m];
                } else {
                    #pragma unroll
                    for (int m = 0; m < 8; ++m){
                        float2 u = cmul(f, spr[m]);
                        if (m == k){ pr[m].x = -u.x;  pr[m].y = -u.y;  }
                        else       { pr[m].x -= u.x;  pr[m].y -= u.y;  }
                    }
                }
            }
            #pragma unroll
            for (int m = 0; m < 8; ++m) Mx[l*ISTR + k0 + m] = pr[m];
        }
        __syncthreads();
        float2 br[8];
        #pragma unroll
        for (int m = 0; m < 8; ++m) br[m] = Mx[(k0+m)*ISTR + l];
        __syncthreads();
        if (((unsigned)(l - k0)) >= 8u){
            #pragma unroll
            for (int rr = 0; rr < 8; ++rr){
                const int r = rbase + rr;
                float2 acc;
                if (((unsigned)(r - k0)) < 8u){ acc.x = 0.f; acc.y = 0.f; }
                else acc = Mx[r*ISTR + l];
                #pragma unroll
                for (int m = 0; m < 8; ++m){
                    float2 Pv = Mx[r*ISTR + k0 + m];
                    acc.x += Pv.x*br[m].x - Pv.y*br[m].y;
                    acc.y += Pv.x*br[m].y + Pv.y*br[m].x;
                }
                Mx[r*ISTR + l] = acc;
            }
        }
        __syncthreads();
    }
    __builtin_amdgcn_s_setprio(0);
    for (int idx = tid; idx < 4096; idx += 512){
        int i = idx >> 6, j = idx & 63;
        Vinv[h*4096 + idx] = Mx[i*ISTR + j];
    }
}

// ---------- W3eff tile (R16-verified): fold V into w_out1 ----------
__device__ __forceinline__ void w3eff_tile(const float* __restrict__ Vr,
        const float* __restrict__ Vi, const float* __restrict__ w3,
        ushort* __restrict__ W3bt, int t, int tid, float* lds){
    const int n0 = (t & 31)*32;
    const int c0 = (t >> 5)*32;
    const int h  = c0 >> 7;
    const int og0 = (c0 & 127) >> 1;
    float* Vbr = lds;            // 64 x 16
    float* Vbi = lds + 1024;     // 64 x 16
    float* Wb  = lds + 2048;     // 128 x 32
    for (int q = tid; q < 1024; q += 512){
        int dd = q >> 4, oo = q & 15;
        Vbr[q] = Vr[(h*64+dd)*64 + og0 + oo];
        Vbi[q] = Vi[(h*64+dd)*64 + og0 + oo];
    }
    for (int q = tid; q < 4096; q += 512){
        int row = q >> 5, nn = q & 31;
        Wb[q] = w3[(h*128 + row)*1024 + n0 + nn];
    }
    __syncthreads();
    const int nn = tid & 31, oo = tid >> 5;    // oo 0..15
    float ar = 0.f, ai = 0.f;
    #pragma unroll 8
    for (int dd = 0; dd < 64; ++dd){
        float vr = Vbr[dd*16 + oo], vi = Vbi[dd*16 + oo];
        float w0 = Wb[(dd*2)*32 + nn], w1v = Wb[(dd*2+1)*32 + nn];
        ar += vr*w0 + vi*w1v;
        ai += -vi*w0 + vr*w1v;
    }
    W3bt[(n0+nn)*1024 + c0 + oo*2 + 0] = f2bf(ar);
    W3bt[(n0+nn)*1024 + c0 + oo*2 + 1] = f2bf(ai);
}

// ---------- prep (pure): w1t + w2t + x->bf16 (no inv, no W3eff, no w4t) ----------
// blocks [0,512): w1t; [512,1536): w2t; [1536,1600): x cvt.
__global__ __launch_bounds__(512) void prep_kernel(
        const float* __restrict__ x,
        const float* __restrict__ w1, const float* __restrict__ w2,
        ushort* __restrict__ x_bf,
        ushort* __restrict__ w1t, ushort* __restrict__ w2t){
    __shared__ __align__(16) char lds_raw[33280];
    const int b = blockIdx.x;
    const int tid = threadIdx.x;
    const int half = tid >> 8;

    int u = b;
    if (u < 1536){
        const float* W; ushort* Wt; const int K = 1024; int N; int t;
        if (u < 512){ W = w1; Wt = w1t; N = 1024; t = u*2 + half; }
        else        { W = w2; Wt = w2t; N = 2048; t = (u-512)*2 + half; }
        const int tiles_n = N >> 5;
        const int n0 = (t % tiles_n) * 32, k0 = (t / tiles_n) * 32;
        float* tile = (float*)lds_raw + half*(32*33);
        const int tx = tid & 31, ty = (tid >> 5) & 7;
        #pragma unroll
        for (int i = 0; i < 4; ++i)
            tile[(ty + i*8)*33 + tx] = W[(k0 + ty + i*8)*N + n0 + tx];
        __syncthreads();
        #pragma unroll
        for (int i = 0; i < 4; ++i){
            int r = ty + i*8;
            Wt[(n0 + r)*K + k0 + tx] = f2bf(tile[tx*33 + r]);
        }
        return;
    }
    u -= 1536;
    // u < 64: x -> bf16, 64 blocks * 512 thr * 2 float4
    const int base = (u*512 + tid)*2;
    #pragma unroll
    for (int j = 0; j < 2; ++j){
        float4 v = ((const float4*)x)[base + j];
        ushort4 uu; uu.x=f2bf(v.x); uu.y=f2bf(v.y); uu.z=f2bf(v.z); uu.w=f2bf(v.w);
        ((ushort4*)x_bf)[base + j] = uu;
    }
}

// ---------- K-split GEMM phase (verbatim R4-verified) ----------
template<int ACT, int KS>
__device__ __forceinline__ void gemm_phase(const ushort* __restrict__ A,
        const ushort* __restrict__ Bt, const float* __restrict__ bias,
        float* __restrict__ Cf, ushort* __restrict__ Cb,
        float2* __restrict__ XCo, float2* __restrict__ Ao,
        int M, int N, int blk, int tid, float* red){
    constexpr int Kw = 1024/KS;
    constexpr int TPBT = 8/KS;
    const int wave = tid >> 6, l = tid & 63;
    const int ml = l & 15, quad = l >> 4;
    const int lt = wave / KS, ks = wave - lt*KS;
    const int tile = blk*TPBT + lt;
    const int tm = M >> 5;
    const int bm = (tile % tm)*32, bn = (tile / tm)*32;
    const ushort* Ap = A  + (bm + ml)*1024 + ks*Kw + quad*8;
    const ushort* Bp = Bt + (bn + ml)*1024 + ks*Kw + quad*8;

    f32x4 acc[2][2];
    #pragma unroll
    for (int i=0;i<2;++i)
        #pragma unroll
        for (int j=0;j<2;++j) acc[i][j] = (f32x4){0.f,0.f,0.f,0.f};

    short8 ac[2], bc[2];
    ac[0] = *(const short8*)(Ap);
    ac[1] = *(const short8*)(Ap + 16*1024);
    bc[0] = *(const short8*)(Bp);
    bc[1] = *(const short8*)(Bp + 16*1024);

    #pragma unroll
    for (int k0 = 32; k0 < Kw; k0 += 32){
        short8 an[2], bn2[2];
        an[0]  = *(const short8*)(Ap + k0);
        an[1]  = *(const short8*)(Ap + 16*1024 + k0);
        bn2[0] = *(const short8*)(Bp + k0);
        bn2[1] = *(const short8*)(Bp + 16*1024 + k0);
        #pragma unroll
        for (int i=0;i<2;++i)
            #pragma unroll
            for (int j=0;j<2;++j)
                acc[i][j] = __builtin_amdgcn_mfma_f32_16x16x32_bf16(ac[i], bc[j], acc[i][j], 0,0,0);
        ac[0]=an[0]; ac[1]=an[1]; bc[0]=bn2[0]; bc[1]=bn2[1];
    }
    #pragma unroll
    for (int i=0;i<2;++i)
        #pragma unroll
        for (int j=0;j<2;++j)
            acc[i][j] = __builtin_amdgcn_mfma_f32_16x16x32_bf16(ac[i], bc[j], acc[i][j], 0,0,0);

    // partial-sum reduction: red[wave][16][64]
    #pragma unroll
    for (int i=0;i<2;++i)
        #pragma unroll
        for (int j=0;j<2;++j)
            #pragma unroll
            for (int r=0;r<4;++r)
                red[wave*1024 + ((i*2+j)*4+r)*64 + l] = acc[i][j][r];
    __syncthreads();

    if (ks == 0){
        #pragma unroll
        for (int i=0;i<2;++i){
            #pragma unroll
            for (int j=0;j<2;++j){
                const int gcol = bn + j*16 + ml;
                const float bsv = bias[gcol];
                #pragma unroll
                for (int r=0;r<4;++r){
                    float val = bsv;
                    #pragma unroll
                    for (int s=0;s<KS;++s)
                        val += red[(wave+s)*1024 + ((i*2+j)*4+r)*64 + l];
                    const int grow = bm + i*16 + quad*4 + r;
                    if (ACT == 2){
                        float v1 = __shfl_down(val, 1);
                        float v2 = __shfl_down(val, 2);
                        float v3 = __shfl_down(val, 3);
                        if ((l & 3) == 0){
                            int hd = gcol >> 2;
                            XCo[grow*HD + hd] = make_float2(val, v1);
                            float m2 = v2*v2 + v3*v3;
                            float s = sqrtf(m2)/(1.f + m2);
                            Ao[grow*HD + hd] = make_float2(v2*s, v3*s);
                        }
                    } else if (ACT == 1){
                        val *= 1.f/(1.f + expf(-val));
                        Cb[grow*N + gcol] = f2bf(val);
                    } else {
                        Cf[grow*N + gcol] = val;
                    }
                }
            }
        }
    }
}

// ---------- D2: inv (blocks 0-7, scheduled first) + gemm1 (8..264) + W3eff riders ----------
__global__ __launch_bounds__(512) void gemm1_inv_w3(const ushort* __restrict__ A,
        const ushort* __restrict__ Bt, const float* __restrict__ bias,
        ushort* __restrict__ Cb,
        const float* __restrict__ Vr, const float* __restrict__ Vi,
        float2* __restrict__ Vinv,
        const float* __restrict__ w3, ushort* __restrict__ W3bt){
    __shared__ __align__(16) char lds_raw[33280];
    const int b = blockIdx.x;
    if (b < 8){
        inv_gj_blocked(Vr, Vi, Vinv, b, threadIdx.x, (float2*)lds_raw);
        return;
    }
    if (b < 264){
        gemm_phase<1,8>(A, Bt, bias, nullptr, Cb, nullptr, nullptr,
                        256, 1024, b - 8, threadIdx.x, (float*)lds_raw);
        return;
    }
    w3eff_tile(Vr, Vi, w3, W3bt, b - 264, threadIdx.x, (float*)lds_raw);
}

// ---------- D3: gemm2 + w4t riders ----------
__global__ __launch_bounds__(512) void gemm2_w4(const ushort* __restrict__ A,
        const ushort* __restrict__ Bt, const float* __restrict__ bias,
        float2* __restrict__ XCo, float2* __restrict__ Ao,
        const float* __restrict__ w4, ushort* __restrict__ w4t){
    __shared__ __align__(16) char lds_raw[33280];
    const int ntb = 256;
    if ((int)blockIdx.x >= ntb){
        const int u = (int)blockIdx.x - ntb;
        const int tid = threadIdx.x;
        const int half = tid >> 8;
        const int t = u*2 + half;
        const int n0 = (t & 31)*32, k0 = (t >> 5)*32;
        float* tile = (float*)lds_raw + half*(32*33);
        const int tx = tid & 31, ty = (tid >> 5) & 7;
        #pragma unroll
        for (int i = 0; i < 4; ++i)
            tile[(ty + i*8)*33 + tx] = w4[(k0 + ty + i*8)*1024 + n0 + tx];
        __syncthreads();
        #pragma unroll
        for (int i = 0; i < 4; ++i){
            int r = ty + i*8;
            w4t[(n0 + r)*1024 + k0 + tx] = f2bf(tile[tx*33 + r]);
        }
        return;
    }
    gemm_phase<2,4>(A, Bt, bias, nullptr, nullptr, XCo, Ao,
                    256, 2048, blockIdx.x, threadIdx.x, (float*)lds_raw);
}

// ---------- standalone K-split GEMM dispatch (verbatim R4). Tail block
// computes the hidden_next tail (gemm3 only, out_tail != nullptr). ----------
template<int ACT, int KS>
__global__ __launch_bounds__(512) void gemm_ks(const ushort* __restrict__ A,
        const ushort* __restrict__ Bt, const float* __restrict__ bias,
        float* __restrict__ Cf, ushort* __restrict__ Cb,
        float2* __restrict__ XCo, float2* __restrict__ Ao,
        int M, int N,
        const float* __restrict__ tVr, const float* __restrict__ tVi,
        const float2* __restrict__ S255, float* __restrict__ out_tail,
        int tail_n){
    __shared__ float red[8*1024];
    const int nt = (M >> 5) * (N >> 5);
    const int ntb = nt / (8/KS);
    if (out_tail != nullptr && blockIdx.x >= ntb){
        if ((threadIdx.x >> 6) == 0 && tail_n >= 512){
            const int l = threadIdx.x & 63;
            for (int hn = l; hn < 512; hn += 64){
                const int h = hn >> 6;
                float2 acc2 = make_float2(0.f, 0.f);
                #pragma unroll 8
                for (int o = 0; o < 64; ++o){
                    float2 v = make_float2(tVr[hn*64+o], tVi[hn*64+o]);
                    float2 p = cmul(v, S255[h*64+o]);
                    acc2.x += p.x; acc2.y += p.y;
                }
                if (tail_n >= 1024){
                    out_tail[hn]       = acc2.x;
                    out_tail[512 + hn] = acc2.y;
                } else {
                    out_tail[hn] = acc2.x;
                }
            }
        }
        return;
    }
    gemm_phase<ACT, KS>(A, Bt, bias, Cf, Cb, XCo, Ao, M, N,
                        blockIdx.x, threadIdx.x, red);
}

// ---------- serial-fallback kernels (R14 path; used only if ws too small) ----------
__global__ __launch_bounds__(512) void inv_kernel(const float* __restrict__ Vr,
                                                  const float* __restrict__ Vi,
                                                  float2* __restrict__ Vinv){
    __shared__ float2 Mx[64*ISTR];
    inv_gj_blocked(Vr, Vi, Vinv, blockIdx.x, threadIdx.x, Mx);
}

__global__ __launch_bounds__(256) void transpose_cvt(const float* __restrict__ W,
                 ushort* __restrict__ Wt, int K, int N){
    __shared__ float tile[32][33];
    const int n0 = blockIdx.x * 32, k0 = blockIdx.y * 32;
    const int tx = threadIdx.x & 31, ty = threadIdx.x >> 5;
    #pragma unroll
    for (int i = 0; i < 4; ++i)
        tile[ty + i*8][tx] = W[(k0 + ty + i*8)*N + n0 + tx];
    __syncthreads();
    #pragma unroll
    for (int i = 0; i < 4; ++i){
        int r = ty + i*8;
        Wt[(n0 + r)*K + k0 + tx] = f2bf(tile[tx][r]);
    }
}

__global__ __launch_bounds__(256) void cvt_bf16_kernel(const float* __restrict__ in,
                                 ushort* __restrict__ o, int n4){
    int i = blockIdx.x*256 + threadIdx.x;
    if (i < n4){
        float4 v = ((const float4*)in)[i];
        ushort4 u; u.x=f2bf(v.x); u.y=f2bf(v.y); u.z=f2bf(v.z); u.w=f2bf(v.w);
        ((ushort4*)o)[i] = u;
    }
}

// ---------- bf16 MFMA GEMM, 64x64 tile (R14-verified). Fallback path only. ----------
#define BM 64
#define BN 64
template<int ACT>
__global__ __launch_bounds__(256) void gemm_bt(const ushort* __restrict__ A,
                 const ushort* __restrict__ Bt, const float* __restrict__ bias,
                 float* __restrict__ Cf, ushort* __restrict__ Cb,
                 float2* __restrict__ XCo, float2* __restrict__ Ao,
                 int M, int N, int K,
                 const float* __restrict__ tVr, const float* __restrict__ tVi,
                 const float2* __restrict__ S255, float* __restrict__ out_tail,
                 int tail_n){
    __shared__ ushort As[BM*ASTR];
    __shared__ ushort Bs[BN*ASTR];
    const int tid = threadIdx.x;
    const int bm = blockIdx.y * BM, bn = blockIdx.x * BN;
    const int wave = tid >> 6, l = tid & 63;
    const int wr = (wave >> 1) * 32, wc = (wave & 1) * 32;
    const int ml = l & 15, quad = l >> 4;

    if (ACT == 0 && out_tail != nullptr && blockIdx.x == 0 && blockIdx.y == 0){
        for (int hn = tid; hn < 512; hn += 256){
            int h = hn >> 6;
            float2 acc2 = make_float2(0.f, 0.f);
            #pragma unroll 8
            for (int o = 0; o < 64; ++o){
                float2 v = make_float2(tVr[hn*64+o], tVi[hn*64+o]);
                float2 p = cmul(v, S255[h*64+o]);
                acc2.x += p.x; acc2.y += p.y;
            }
            if (tail_n >= 1024){
                out_tail[hn]       = acc2.x;
                out_tail[512 + hn] = acc2.y;
            } else if (tail_n >= 512){
                out_tail[hn] = acc2.x;
            }
        }
    }

    f32x4 acc[2][2];
    #pragma unroll
    for (int i=0;i<2;++i)
        #pragma unroll
        for (int j=0;j<2;++j) acc[i][j] = (f32x4){0.f,0.f,0.f,0.f};
    const int c0r = tid >> 2;
    const int c0s = tid & 3;
    for (int k0 = 0; k0 < K; k0 += BK){
        uint4 av = *(const uint4*)&A [(bm + c0r)*K + k0 + c0s*8];
        uint4 bv = *(const uint4*)&Bt[(bn + c0r)*K + k0 + c0s*8];
        __syncthreads();
        *(uint4*)&As[c0r*ASTR + c0s*8] = av;
        *(uint4*)&Bs[c0r*ASTR + c0s*8] = bv;
        __syncthreads();
        short8 af[2], bfv[2];
        #pragma unroll
        for (int f=0; f<2; ++f){
            af[f]  = *(const short8*)&As[(wr + f*16 + ml)*ASTR + quad*8];
            bfv[f] = *(const short8*)&Bs[(wc + f*16 + ml)*ASTR + quad*8];
        }
        #pragma unroll
        for (int i=0;i<2;++i)
            #pragma unroll
            for (int j=0;j<2;++j)
                acc[i][j] = __builtin_amdgcn_mfma_f32_16x16x32_bf16(af[i], bfv[j], acc[i][j], 0,0,0);
    }
    #pragma unroll
    for (int i=0;i<2;++i){
        #pragma unroll
        for (int j=0;j<2;++j){
            const int gcol = bn + wc + j*16 + ml;
            const float bsv = bias[gcol];
            #pragma unroll
            for (int r=0;r<4;++r){
                const int grow = bm + wr + i*16 + quad*4 + r;
                float val = acc[i][j][r] + bsv;
                if (ACT == 2){
                    float v1 = __shfl_down(val, 1);
                    float v2 = __shfl_down(val, 2);
                    float v3 = __shfl_down(val, 3);
                    if ((l & 3) == 0){
                        int hd = gcol >> 2;
                        XCo[grow*HD + hd] = make_float2(val, v1);
                        float m2 = v2*v2 + v3*v3;
                        float s = sqrtf(m2)/(1.f + m2);
                        Ao[grow*HD + hd] = make_float2(v2*s, v3*s);
                    }
                } else if (ACT == 1){
                    val *= 1.f/(1.f + expf(-val));
                    Cb[grow*N + gcol] = f2bf(val);
                } else {
                    Cf[grow*N + gcol] = val;
                }
            }
        }
    }
}

// ---------- fused uext + parallel scan; writes Sb (bf16, hr-layout) + S255 fp32 ----------
__global__ __launch_bounds__(512) void upscan_kernel(const float2* __restrict__ Vinv,
        const float* __restrict__ hidr, const float* __restrict__ him,
        const float2* __restrict__ XC, const float2* __restrict__ Aseq,
        ushort* __restrict__ Sb, float2* __restrict__ S255){
    __shared__ float4 buf[2][2][LSEQ];
    __shared__ float2 vrow[2][64];
    __shared__ float2 inu[2];
    const int b = blockIdx.x;
    const int tid = threadIdx.x;
    const int g = tid >> 8, m = tid & 255;
    const int hn = b*2 + g;
    const int h = hn >> 6;
    if (m < 64) vrow[g][m] = Vinv[hn*64 + m];
    __syncthreads();
    float2 acc = make_float2(0.f, 0.f);
    const float2* xrow = &XC[m*HD + h*64];
    #pragma unroll 8
    for (int o=0;o<64;++o){
        float2 p = cmul(vrow[g][o], xrow[o]);
        acc.x += p.x; acc.y += p.y;
    }
    if (m == 0){
        float2 i0 = make_float2(0.f, 0.f);
        #pragma unroll 8
        for (int o=0;o<64;++o){
            float2 hv = make_float2(hidr[h*64+o], him[h*64+o]);
            float2 p = cmul(vrow[g][o], hv);
            i0.x += p.x; i0.y += p.y;
        }
        inu[g] = i0;
    }
    float2 a = Aseq[m*HD + hn];
    buf[0][g][m] = make_float4(a.x, a.y, acc.x, acc.y);
    __syncthreads();
    int pb = 0;
    #pragma unroll
    for (int d = 1; d < LSEQ; d <<= 1){
        float4 cur = buf[pb][g][m];
        float4 o2 = cur;
        if (m >= d){
            float4 prev = buf[pb][g][m-d];
            float2 cA = make_float2(cur.x, cur.y), cU = make_float2(cur.z, cur.w);
            float2 pA = make_float2(prev.x, prev.y), pU = make_float2(prev.z, prev.w);
            float2 nA = cmul(cA, pA);
            float2 nU = cmul(cA, pU);
            nU.x += cU.x; nU.y += cU.y;
            o2 = make_float4(nA.x, nA.y, nU.x, nU.y);
        }
        buf[pb^1][g][m] = o2;
        pb ^= 1;
        __syncthreads();
    }
    float4 t = buf[pb][g][m];
    float2 init = inu[g];
    float2 st = cmul(make_float2(t.x, t.y), init);
    st.x += t.z; st.y += t.w;
    Sb[m*DIMN + hn*2]   = f2bf(st.x);
    Sb[m*DIMN + hn*2+1] = f2bf(st.y);
    if (m == LSEQ-1) S255[hn] = st;
}

// ---------- fallback-only kernels ----------
__global__ __launch_bounds__(256) void vmul_kernel(const float* __restrict__ Vr,
                            const float* __restrict__ Vi,
                            const float2* __restrict__ S, ushort* __restrict__ hrb,
                            float* __restrict__ out_tail, int tail_n){
    int g = blockIdx.x*256 + threadIdx.x;
    int m = g >> 9, hn = g & 511;
    int h = hn >> 6;
    const float* vr = &Vr[hn*64];
    const float* vi = &Vi[hn*64];
    const float2* srow = &S[m*HD + h*64];
    float2 acc = make_float2(0.f, 0.f);
    #pragma unroll 8
    for (int o=0;o<64;++o){
        float2 v = make_float2(vr[o], vi[o]);
        float2 p = cmul(v, srow[o]);
        acc.x += p.x; acc.y += p.y;
    }
    hrb[m*DIMN + hn*2]   = f2bf(acc.x);
    hrb[m*DIMN + hn*2+1] = f2bf(acc.y);
    if (m == LSEQ-1){
        if (tail_n >= 1024){
            out_tail[hn]       = acc.x;
            out_tail[512 + hn] = acc.y;
        } else if (tail_n >= 512){
            out_tail[hn] = acc.x;
        }
    }
}

__global__ __launch_bounds__(512) void upscan_f32_kernel(const float2* __restrict__ Vinv,
        const float* __restrict__ hidr, const float* __restrict__ him,
        const float2* __restrict__ XC, const float2* __restrict__ Aseq,
        float2* __restrict__ S){
    __shared__ float4 buf[2][2][LSEQ];
    __shared__ float2 vrow[2][64];
    __shared__ float2 inu[2];
    const int b = blockIdx.x;
    const int tid = threadIdx.x;
    const int g = tid >> 8, m = tid & 255;
    const int hn = b*2 + g;
    const int h = hn >> 6;
    if (m < 64) vrow[g][m] = Vinv[hn*64 + m];
    __syncthreads();
    float2 acc = make_float2(0.f, 0.f);
    const float2* xrow = &XC[m*HD + h*64];
    #pragma unroll 8
    for (int o=0;o<64;++o){
        float2 p = cmul(vrow[g][o], xrow[o]);
        acc.x += p.x; acc.y += p.y;
    }
    if (m == 0){
        float2 i0 = make_float2(0.f, 0.f);
        #pragma unroll 8
        for (int o=0;o<64;++o){
            float2 hv = make_float2(hidr[h*64+o], him[h*64+o]);
            float2 p = cmul(vrow[g][o], hv);
            i0.x += p.x; i0.y += p.y;
        }
        inu[g] = i0;
    }
    float2 a = Aseq[m*HD + hn];
    buf[0][g][m] = make_float4(a.x, a.y, acc.x, acc.y);
    __syncthreads();
    int pb = 0;
    #pragma unroll
    for (int d = 1; d < LSEQ; d <<= 1){
        float4 cur = buf[pb][g][m];
        float4 o2 = cur;
        if (m >= d){
            float4 prev = buf[pb][g][m-d];
            float2 cA = make_float2(cur.x, cur.y), cU = make_float2(cur.z, cur.w);
            float2 pA = make_float2(prev.x, prev.y), pU = make_float2(prev.z, prev.w);
            float2 nA = cmul(cA, pA);
            float2 nU = cmul(cA, pU);
            nU.x += cU.x; nU.y += cU.y;
            o2 = make_float4(nA.x, nA.y, nU.x, nU.y);
        }
        buf[pb^1][g][m] = o2;
        pb ^= 1;
        __syncthreads();
    }
    float4 t = buf[pb][g][m];
    float2 init = inu[g];
    float2 st = cmul(make_float2(t.x, t.y), init);
    st.x += t.z; st.y += t.w;
    S[m*HD + hn] = st;
}

extern "C" void kernel_launch(void* const* d_in, const int* in_sizes, int n_in,
                              void* d_out, int out_size, void* d_ws, size_t ws_size,
                              hipStream_t stream) {
    const float* x      = (const float*)d_in[0];
    const float* hidr   = (const float*)d_in[1];
    const float* hidi   = (const float*)d_in[2];
    const float* w_in1  = (const float*)d_in[3];
    const float* b_in1  = (const float*)d_in[4];
    const float* w_in2  = (const float*)d_in[5];
    const float* b_in2  = (const float*)d_in[6];
    const float* w_out1 = (const float*)d_in[7];
    const float* b_out1 = (const float*)d_in[8];
    const float* w_out2 = (const float*)d_in[9];
    const float* b_out2 = (const float*)d_in[10];
    const float* Vr     = (const float*)d_in[11];
    const float* Vi     = (const float*)d_in[12];
    float* out = (float*)d_out;
    const int tail_n = out_size - LSEQ*DIMN;
    char* ws = (char*)d_ws;

    if (ws_size >= 14946304u){
        // lifetime-aliased layout (identical to R10-green):
        //   Vinv  [0, 256K)            D2(inv)->D4
        //   w2t   [256K, 4.25M)        D1->D3
        //   W3bt  [4.25M, 6.25M)       D2(ride)->D5
        //   w4t   [6.25M, 8.25M)       D3(ride)->D6
        //   w1t   [8.25M, 10.25M)      D1->D2   } reused D3+: XC(1M)+Aseq(1M)
        //   x_bf  [10.25M, 10.75M)     D1->D2   } reused D4+: S255(4K)
        //   t1_bf [10.75M, 11.25M)     D2->D3   } reused D4+: Sb
        //   y1_bf [11.25M, 11.75M)     D5->D6
        float2* Vinv  = (float2*)(ws + 0);
        ushort* w2t   = (ushort*)(ws + 262144);
        ushort* W3bt  = (ushort*)(ws + 4456448);
        ushort* w4t   = (ushort*)(ws + 6553600);
        ushort* w1t   = (ushort*)(ws + 8650752);
        float2* XC    = (float2*)(ws + 8650752);
        float2* Aseq  = (float2*)(ws + 9699328);
        ushort* x_bf  = (ushort*)(ws + 10747904);
        float2* S255  = (float2*)(ws + 10747904);
        ushort* t1_bf = (ushort*)(ws + 11272192);
        ushort* y1_bf = (ushort*)(ws + 11796480);
        ushort* Sb    = t1_bf;

        // D1: pure prep (w1t + w2t + x_bf) — no inv
        prep_kernel<<<1600, 512, 0, stream>>>(x, w_in1, w_in2, x_bf, w1t, w2t);
        // D2: inv (blocks 0-7, first, setprio(1)) + gemm1 (256) + W3eff riders (1024)
        gemm1_inv_w3<<<1288, 512, 0, stream>>>(x_bf, w1t, b_in1, t1_bf,
                Vr, Vi, Vinv, w_out1, W3bt);
        // D3: gemm2 (256) + w4t riders (512)
        gemm2_w4<<<768, 512, 0, stream>>>(t1_bf, w2t, b_in2, XC, Aseq, w_out2, w4t);
        // D4: upscan
        upscan_kernel<<<256, 512, 0, stream>>>(Vinv, hidr, hidi, XC, Aseq, Sb, S255);
        // D5: gemm3 + hidden_next tail
        gemm_ks<1,8><<<257, 512, 0, stream>>>(Sb, W3bt, b_out1, nullptr, y1_bf,
                nullptr, nullptr, LSEQ, DIMN, Vr, Vi, S255, out + LSEQ*DIMN, tail_n);
        // D6: gemm4
        gemm_ks<0,8><<<256, 512, 0, stream>>>(y1_bf, w4t, b_out2, out, nullptr,
                nullptr, nullptr, LSEQ, DIMN, nullptr, nullptr, nullptr, nullptr, 0);
    } else {
        // ---- R14 fallback: serial prep + full vmul path ----
        float2* Vinv  = (float2*)(ws + 0);
        ushort* wt    = (ushort*)(ws + 262144);
        ushort* x_bf  = (ushort*)(ws + 4456448);
        ushort* t1_bf = (ushort*)(ws + 4980736);
        float2* XC    = (float2*)(ws + 5505024);
        float2* Aseq  = (float2*)(ws + 6553600);
        float2* S     = (float2*)(ws + 7602176);
        ushort* y1_bf = x_bf;
        ushort* hr_bf = t1_bf;

        inv_kernel<<<NH, 512, 0, stream>>>(Vr, Vi, Vinv);
        cvt_bf16_kernel<<<LSEQ*DIMN/4/256, 256, 0, stream>>>(x, x_bf, LSEQ*DIMN/4);
        transpose_cvt<<<dim3(32,32), 256, 0, stream>>>(w_in1, wt, DIMN, DIMN);
        gemm_bt<1><<<dim3(16,4), 256, 0, stream>>>(x_bf, wt, b_in1, nullptr, t1_bf,
                nullptr, nullptr, LSEQ, DIMN, DIMN, nullptr, nullptr, nullptr, nullptr, 0);
        transpose_cvt<<<dim3(64,32), 256, 0, stream>>>(w_in2, wt, DIMN, 2048);
        gemm_bt<2><<<dim3(32,4), 256, 0, stream>>>(t1_bf, wt, b_in2, nullptr, nullptr,
                XC, Aseq, LSEQ, 2048, DIMN, nullptr, nullptr, nullptr, nullptr, 0);
        upscan_f32_kernel<<<256, 512, 0, stream>>>(Vinv, hidr, hidi, XC, Aseq, S);
        vmul_kernel<<<LSEQ*HD/256, 256, 0, stream>>>(Vr, Vi, S, hr_bf, out + LSEQ*DIMN, tail_n);
        transpose_cvt<<<dim3(32,32), 256, 0, stream>>>(w_out1, wt, DIMN, DIMN);
        gemm_bt<1><<<dim3(16,4), 256, 0, stream>>>(hr_bf, wt, b_out1, nullptr, y1_bf,
                nullptr, nullptr, LSEQ, DIMN, DIMN, nullptr, nullptr, nullptr, nullptr, 0);
        transpose_cvt<<<dim3(32,32), 256, 0, stream>>>(w_out2, wt, DIMN, DIMN);
        gemm_bt<0><<<dim3(16,4), 256, 0, stream>>>(y1_bf, wt, b_out2, out, nullptr,
                nullptr, nullptr, LSEQ, DIMN, DIMN, nullptr, nullptr, nullptr, nullptr, 0);
    }
}

// Round 12
// 185.409 us; speedup vs baseline: 1.5619x; 1.0371x over previous
//
#include <hip/hip_runtime.h>
#include <math.h>

#define DIMN 1024
#define NH 8
#define ND 64
#define LSEQ 256
#define HD 512      // NH*ND

typedef __attribute__((ext_vector_type(8))) short short8;
typedef __attribute__((ext_vector_type(4))) float f32x4;

__device__ __forceinline__ float2 cmul(float2 a, float2 b){
    return make_float2(a.x*b.x - a.y*b.y, a.x*b.y + a.y*b.x);
}
__device__ __forceinline__ ushort f2bf(float f){
    union { float f; unsigned u; } v; v.f = f;
    unsigned r = v.u + 0x7FFF + ((v.u >> 16) & 1);   // RNE
    return (ushort)(r >> 16);
}

#define ISTR 65
#define ASTR 40
#define BK 32

// ---------- blocked (NB=8) in-place Gauss-Jordan (R11/R14-verified body,
// + R11 setprio: inv is issue-starved when co-resident; priority recovers
// 60->46us, measured). ----------
__device__ __forceinline__ void inv_gj_blocked(const float* __restrict__ Vr,
        const float* __restrict__ Vi, float2* __restrict__ Vinv,
        int h, int tid, float2* Mx){
    __builtin_amdgcn_s_setprio(1);
    for (int idx = tid; idx < 4096; idx += 512){
        int i = idx >> 6, j = idx & 63;
        Mx[i*ISTR + j] = make_float2(Vr[h*4096 + idx], Vi[h*4096 + idx]);
    }
    __syncthreads();
    const int w = tid >> 6, l = tid & 63;
    const int rbase = w*8;
    for (int kb = 0; kb < 8; ++kb){
        const int k0 = kb*8;
        if (w == 0){
            float2 pr[8];
            #pragma unroll
            for (int m = 0; m < 8; ++m) pr[m] = Mx[l*ISTR + k0 + m];
            #pragma unroll
            for (int k = 0; k < 8; ++k){
                const int gk = k0 + k;
                float2 d; d.x = __shfl(pr[k].x, gk); d.y = __shfl(pr[k].y, gk);
                float im = 1.f/(d.x*d.x + d.y*d.y);
                float2 p = make_float2(d.x*im, -d.y*im);
                float2 spr[8];
                #pragma unroll
                for (int m = 0; m < 8; ++m){
                    float2 t; t.x = __shfl(pr[m].x, gk); t.y = __shfl(pr[m].y, gk);
                    spr[m] = (m == k) ? p : cmul(t, p);
                }
                float2 f = pr[k];
                if (l == gk){
                    #pragma unroll
                    for (int m = 0; m < 8; ++m) pr[m] = spr[m];
                } else {
                    #pragma unroll
                    for (int m = 0; m < 8; ++m){
                        float2 u = cmul(f, spr[m]);
                        if (m == k){ pr[m].x = -u.x;  pr[m].y = -u.y;  }
                        else       { pr[m].x -= u.x;  pr[m].y -= u.y;  }
                    }
                }
            }
            #pragma unroll
            for (int m = 0; m < 8; ++m) Mx[l*ISTR + k0 + m] = pr[m];
        }
        __syncthreads();
        float2 br[8];
        #pragma unroll
        for (int m = 0; m < 8; ++m) br[m] = Mx[(k0+m)*ISTR + l];
        __syncthreads();
        if (((unsigned)(l - k0)) >= 8u){
            #pragma unroll
            for (int rr = 0; rr < 8; ++rr){
                const int r = rbase + rr;
                float2 acc;
                if (((unsigned)(r - k0)) < 8u){ acc.x = 0.f; acc.y = 0.f; }
                else acc = Mx[r*ISTR + l];
                #pragma unroll
                for (int m = 0; m < 8; ++m){
                    float2 Pv = Mx[r*ISTR + k0 + m];
                    acc.x += Pv.x*br[m].x - Pv.y*br[m].y;
                    acc.y += Pv.x*br[m].y + Pv.y*br[m].x;
                }
                Mx[r*ISTR + l] = acc;
            }
        }
        __syncthreads();
    }
    __builtin_amdgcn_s_setprio(0);
    for (int idx = tid; idx < 4096; idx += 512){
        int i = idx >> 6, j = idx & 63;
        Vinv[h*4096 + idx] = Mx[i*ISTR + j];
    }
}

// ---------- W3eff tile (R16-verified): fold V into w_out1 ----------
__device__ __forceinline__ void w3eff_tile(const float* __restrict__ Vr,
        const float* __restrict__ Vi, const float* __restrict__ w3,
        ushort* __restrict__ W3bt, int t, int tid, float* lds){
    const int n0 = (t & 31)*32;
    const int c0 = (t >> 5)*32;
    const int h  = c0 >> 7;
    const int og0 = (c0 & 127) >> 1;
    float* Vbr = lds;            // 64 x 16
    float* Vbi = lds + 1024;     // 64 x 16
    float* Wb  = lds + 2048;     // 128 x 32
    for (int q = tid; q < 1024; q += 512){
        int dd = q >> 4, oo = q & 15;
        Vbr[q] = Vr[(h*64+dd)*64 + og0 + oo];
        Vbi[q] = Vi[(h*64+dd)*64 + og0 + oo];
    }
    for (int q = tid; q < 4096; q += 512){
        int row = q >> 5, nn = q & 31;
        Wb[q] = w3[(h*128 + row)*1024 + n0 + nn];
    }
    __syncthreads();
    const int nn = tid & 31, oo = tid >> 5;    // oo 0..15
    float ar = 0.f, ai = 0.f;
    #pragma unroll 8
    for (int dd = 0; dd < 64; ++dd){
        float vr = Vbr[dd*16 + oo], vi = Vbi[dd*16 + oo];
        float w0 = Wb[(dd*2)*32 + nn], w1v = Wb[(dd*2+1)*32 + nn];
        ar += vr*w0 + vi*w1v;
        ai += -vi*w0 + vr*w1v;
    }
    W3bt[(n0+nn)*1024 + c0 + oo*2 + 0] = f2bf(ar);
    W3bt[(n0+nn)*1024 + c0 + oo*2 + 1] = f2bf(ai);
}

// ---------- gemm1 direct tile (R0-verified): one 64x64 tile by a 256-thread
// half-block. A = x (fp32, converted in-register); B = w1 (fp32 K x N,
// coalesced row reads + in-LDS transpose). Epilogue: silu -> bf16 t1. Both
// halves of a 512-thread block run identical loop/barrier counts. ----------
__device__ __forceinline__ void gemm1_direct_tile(const float* __restrict__ x,
        const float* __restrict__ w1, const float* __restrict__ bias,
        ushort* __restrict__ Cb, int tile, int tid8, ushort* lds){
    ushort* As = lds;                  // 64*ASTR
    ushort* Bs = lds + 64*ASTR;        // 64*ASTR
    const int bm = (tile & 3)*64, bn = (tile >> 2)*64;
    const int wave = tid8 >> 6, l = tid8 & 63;
    const int wr = (wave >> 1)*32, wc = (wave & 1)*32;
    const int ml = l & 15, quad = l >> 4;
    f32x4 acc[2][2];
    #pragma unroll
    for (int i=0;i<2;++i)
        #pragma unroll
        for (int j=0;j<2;++j) acc[i][j] = (f32x4){0.f,0.f,0.f,0.f};
    const int c0r = tid8 >> 2, c0s = tid8 & 3;
    const int bn_n = tid8 & 63, bk0 = (tid8 >> 6)*8;
    for (int k0 = 0; k0 < DIMN; k0 += BK){
        float4 a0 = *(const float4*)&x[(bm+c0r)*DIMN + k0 + c0s*8];
        float4 a1 = *(const float4*)&x[(bm+c0r)*DIMN + k0 + c0s*8 + 4];
        float bv[8];
        #pragma unroll
        for (int kk = 0; kk < 8; ++kk)
            bv[kk] = w1[(k0 + bk0 + kk)*DIMN + bn + bn_n];
        __syncthreads();
        ushort4 u0; u0.x=f2bf(a0.x); u0.y=f2bf(a0.y); u0.z=f2bf(a0.z); u0.w=f2bf(a0.w);
        ushort4 u1; u1.x=f2bf(a1.x); u1.y=f2bf(a1.y); u1.z=f2bf(a1.z); u1.w=f2bf(a1.w);
        *(ushort4*)&As[c0r*ASTR + c0s*8]     = u0;
        *(ushort4*)&As[c0r*ASTR + c0s*8 + 4] = u1;
        #pragma unroll
        for (int kk = 0; kk < 8; ++kk)
            Bs[bn_n*ASTR + bk0 + kk] = f2bf(bv[kk]);
        __syncthreads();
        short8 af[2], bfv[2];
        #pragma unroll
        for (int f=0; f<2; ++f){
            af[f]  = *(const short8*)&As[(wr + f*16 + ml)*ASTR + quad*8];
            bfv[f] = *(const short8*)&Bs[(wc + f*16 + ml)*ASTR + quad*8];
        }
        #pragma unroll
        for (int i=0;i<2;++i)
            #pragma unroll
            for (int j=0;j<2;++j)
                acc[i][j] = __builtin_amdgcn_mfma_f32_16x16x32_bf16(af[i], bfv[j], acc[i][j], 0,0,0);
    }
    #pragma unroll
    for (int i=0;i<2;++i){
        #pragma unroll
        for (int j=0;j<2;++j){
            const int gcol = bn + wc + j*16 + ml;
            const float bsv = bias[gcol];
            #pragma unroll
            for (int r=0;r<4;++r){
                const int grow = bm + wr + i*16 + quad*4 + r;
                float val = acc[i][j][r] + bsv;
                val *= 1.f/(1.f + expf(-val));
                Cb[grow*DIMN + gcol] = f2bf(val);
            }
        }
    }
}

// ---------- D1 mix1 (R0-verified layout): gemm1(direct) + inv + w2t/w4t + W3eff ----------
// blocks 0-31: gemm1 (2 tiles each, 64 tiles); 32-39: inv;
// 40-1063: w2t (2048 tiles); 1064-1575: w4t (1024 tiles); 1576-2599: W3eff.
__global__ __launch_bounds__(512) void mix1_kernel(
        const float* __restrict__ x,
        const float* __restrict__ w1, const float* __restrict__ w2,
        const float* __restrict__ w3, const float* __restrict__ w4,
        const float* __restrict__ Vr, const float* __restrict__ Vi,
        const float* __restrict__ b1,
        ushort* __restrict__ t1_bf,
        ushort* __restrict__ w2t, ushort* __restrict__ W3bt,
        ushort* __restrict__ w4t, float2* __restrict__ Vinv){
    __shared__ __align__(16) char lds_raw[33280];
    const int b = blockIdx.x;
    const int tid = threadIdx.x;
    const int half = tid >> 8;

    if (b < 32){
        gemm1_direct_tile(x, w1, b1, t1_bf, b*2 + half, tid & 255,
                          (ushort*)lds_raw + half*(128*ASTR));
        return;
    }
    if (b < 40){
        inv_gj_blocked(Vr, Vi, Vinv, b - 32, tid, (float2*)lds_raw);
        return;
    }
    int widx = b - 40;
    if (widx >= 1536){
        w3eff_tile(Vr, Vi, w3, W3bt, widx - 1536, tid, (float*)lds_raw);
        return;
    }
    const float* W; ushort* Wt; int K = 1024, N;
    if (widx < 1024){ W = w2; Wt = w2t; N = 2048; }
    else            { W = w4; Wt = w4t; N = 1024; widx -= 1024; }
    const int t = widx*2 + half;
    const int tiles_n = N >> 5;
    const int n0 = (t % tiles_n) * 32, k0 = (t / tiles_n) * 32;
    float* tile = (float*)lds_raw + half*(32*33);
    const int tx = tid & 31, ty = (tid >> 5) & 7;
    #pragma unroll
    for (int i = 0; i < 4; ++i)
        tile[(ty + i*8)*33 + tx] = W[(k0 + ty + i*8)*N + n0 + tx];
    __syncthreads();
    #pragma unroll
    for (int i = 0; i < 4; ++i){
        int r = ty + i*8;
        Wt[(n0 + r)*K + k0 + tx] = f2bf(tile[tx*33 + r]);
    }
}

// ---------- K-split GEMM phase (verbatim R4-verified) ----------
template<int ACT, int KS>
__device__ __forceinline__ void gemm_phase(const ushort* __restrict__ A,
        const ushort* __restrict__ Bt, const float* __restrict__ bias,
        float* __restrict__ Cf, ushort* __restrict__ Cb,
        float2* __restrict__ XCo, float2* __restrict__ Ao,
        int M, int N, int blk, int tid, float* red){
    constexpr int Kw = 1024/KS;
    constexpr int TPBT = 8/KS;
    const int wave = tid >> 6, l = tid & 63;
    const int ml = l & 15, quad = l >> 4;
    const int lt = wave / KS, ks = wave - lt*KS;
    const int tile = blk*TPBT + lt;
    const int tm = M >> 5;
    const int bm = (tile % tm)*32, bn = (tile / tm)*32;
    const ushort* Ap = A  + (bm + ml)*1024 + ks*Kw + quad*8;
    const ushort* Bp = Bt + (bn + ml)*1024 + ks*Kw + quad*8;

    f32x4 acc[2][2];
    #pragma unroll
    for (int i=0;i<2;++i)
        #pragma unroll
        for (int j=0;j<2;++j) acc[i][j] = (f32x4){0.f,0.f,0.f,0.f};

    short8 ac[2], bc[2];
    ac[0] = *(const short8*)(Ap);
    ac[1] = *(const short8*)(Ap + 16*1024);
    bc[0] = *(const short8*)(Bp);
    bc[1] = *(const short8*)(Bp + 16*1024);

    #pragma unroll
    for (int k0 = 32; k0 < Kw; k0 += 32){
        short8 an[2], bn2[2];
        an[0]  = *(const short8*)(Ap + k0);
        an[1]  = *(const short8*)(Ap + 16*1024 + k0);
        bn2[0] = *(const short8*)(Bp + k0);
        bn2[1] = *(const short8*)(Bp + 16*1024 + k0);
        #pragma unroll
        for (int i=0;i<2;++i)
            #pragma unroll
            for (int j=0;j<2;++j)
                acc[i][j] = __builtin_amdgcn_mfma_f32_16x16x32_bf16(ac[i], bc[j], acc[i][j], 0,0,0);
        ac[0]=an[0]; ac[1]=an[1]; bc[0]=bn2[0]; bc[1]=bn2[1];
    }
    #pragma unroll
    for (int i=0;i<2;++i)
        #pragma unroll
        for (int j=0;j<2;++j)
            acc[i][j] = __builtin_amdgcn_mfma_f32_16x16x32_bf16(ac[i], bc[j], acc[i][j], 0,0,0);

    // partial-sum reduction: red[wave][16][64]
    #pragma unroll
    for (int i=0;i<2;++i)
        #pragma unroll
        for (int j=0;j<2;++j)
            #pragma unroll
            for (int r=0;r<4;++r)
                red[wave*1024 + ((i*2+j)*4+r)*64 + l] = acc[i][j][r];
    __syncthreads();

    if (ks == 0){
        #pragma unroll
        for (int i=0;i<2;++i){
            #pragma unroll
            for (int j=0;j<2;++j){
                const int gcol = bn + j*16 + ml;
                const float bsv = bias[gcol];
                #pragma unroll
                for (int r=0;r<4;++r){
                    float val = bsv;
                    #pragma unroll
                    for (int s=0;s<KS;++s)
                        val += red[(wave+s)*1024 + ((i*2+j)*4+r)*64 + l];
                    const int grow = bm + i*16 + quad*4 + r;
                    if (ACT == 2){
                        float v1 = __shfl_down(val, 1);
                        float v2 = __shfl_down(val, 2);
                        float v3 = __shfl_down(val, 3);
                        if ((l & 3) == 0){
                            int hd = gcol >> 2;
                            XCo[grow*HD + hd] = make_float2(val, v1);
                            float m2 = v2*v2 + v3*v3;
                            float s = sqrtf(m2)/(1.f + m2);
                            Ao[grow*HD + hd] = make_float2(v2*s, v3*s);
                        }
                    } else if (ACT == 1){
                        val *= 1.f/(1.f + expf(-val));
                        Cb[grow*N + gcol] = f2bf(val);
                    } else {
                        Cf[grow*N + gcol] = val;
                    }
                }
            }
        }
    }
}

// ---------- standalone K-split GEMM dispatch (verbatim R4). Tail block
// computes the hidden_next tail (gemm3 only, out_tail != nullptr). ----------
template<int ACT, int KS>
__global__ __launch_bounds__(512) void gemm_ks(const ushort* __restrict__ A,
        const ushort* __restrict__ Bt, const float* __restrict__ bias,
        float* __restrict__ Cf, ushort* __restrict__ Cb,
        float2* __restrict__ XCo, float2* __restrict__ Ao,
        int M, int N,
        const float* __restrict__ tVr, const float* __restrict__ tVi,
        const float2* __restrict__ S255, float* __restrict__ out_tail,
        int tail_n){
    __shared__ float red[8*1024];
    const int nt = (M >> 5) * (N >> 5);
    const int ntb = nt / (8/KS);
    if (out_tail != nullptr && blockIdx.x >= ntb){
        if ((threadIdx.x >> 6) == 0 && tail_n >= 512){
            const int l = threadIdx.x & 63;
            for (int hn = l; hn < 512; hn += 64){
                const int h = hn >> 6;
                float2 acc2 = make_float2(0.f, 0.f);
                #pragma unroll 8
                for (int o = 0; o < 64; ++o){
                    float2 v = make_float2(tVr[hn*64+o], tVi[hn*64+o]);
                    float2 p = cmul(v, S255[h*64+o]);
                    acc2.x += p.x; acc2.y += p.y;
                }
                if (tail_n >= 1024){
                    out_tail[hn]       = acc2.x;
                    out_tail[512 + hn] = acc2.y;
                } else {
                    out_tail[hn] = acc2.x;
                }
            }
        }
        return;
    }
    gemm_phase<ACT, KS>(A, Bt, bias, Cf, Cb, XCo, Ao, M, N,
                        blockIdx.x, threadIdx.x, red);
}

// ---------- serial-fallback kernels (R14 path; used only if ws too small) ----------
__global__ __launch_bounds__(512) void inv_kernel(const float* __restrict__ Vr,
                                                  const float* __restrict__ Vi,
                                                  float2* __restrict__ Vinv){
    __shared__ float2 Mx[64*ISTR];
    inv_gj_blocked(Vr, Vi, Vinv, blockIdx.x, threadIdx.x, Mx);
}

__global__ __launch_bounds__(256) void transpose_cvt(const float* __restrict__ W,
                 ushort* __restrict__ Wt, int K, int N){
    __shared__ float tile[32][33];
    const int n0 = blockIdx.x * 32, k0 = blockIdx.y * 32;
    const int tx = threadIdx.x & 31, ty = threadIdx.x >> 5;
    #pragma unroll
    for (int i = 0; i < 4; ++i)
        tile[ty + i*8][tx] = W[(k0 + ty + i*8)*N + n0 + tx];
    __syncthreads();
    #pragma unroll
    for (int i = 0; i < 4; ++i){
        int r = ty + i*8;
        Wt[(n0 + r)*K + k0 + tx] = f2bf(tile[tx][r]);
    }
}

__global__ __launch_bounds__(256) void cvt_bf16_kernel(const float* __restrict__ in,
                                 ushort* __restrict__ o, int n4){
    int i = blockIdx.x*256 + threadIdx.x;
    if (i < n4){
        float4 v = ((const float4*)in)[i];
        ushort4 u; u.x=f2bf(v.x); u.y=f2bf(v.y); u.z=f2bf(v.z); u.w=f2bf(v.w);
        ((ushort4*)o)[i] = u;
    }
}

// ---------- bf16 MFMA GEMM, 64x64 tile (R14-verified). Fallback path only. ----------
#define BM 64
#define BN 64
template<int ACT>
__global__ __launch_bounds__(256) void gemm_bt(const ushort* __restrict__ A,
                 const ushort* __restrict__ Bt, const float* __restrict__ bias,
                 float* __restrict__ Cf, ushort* __restrict__ Cb,
                 float2* __restrict__ XCo, float2* __restrict__ Ao,
                 int M, int N, int K,
                 const float* __restrict__ tVr, const float* __restrict__ tVi,
                 const float2* __restrict__ S255, float* __restrict__ out_tail,
                 int tail_n){
    __shared__ ushort As[BM*ASTR];
    __shared__ ushort Bs[BN*ASTR];
    const int tid = threadIdx.x;
    const int bm = blockIdx.y * BM, bn = blockIdx.x * BN;
    const int wave = tid >> 6, l = tid & 63;
    const int wr = (wave >> 1) * 32, wc = (wave & 1) * 32;
    const int ml = l & 15, quad = l >> 4;

    if (ACT == 0 && out_tail != nullptr && blockIdx.x == 0 && blockIdx.y == 0){
        for (int hn = tid; hn < 512; hn += 256){
            int h = hn >> 6;
            float2 acc2 = make_float2(0.f, 0.f);
            #pragma unroll 8
            for (int o = 0; o < 64; ++o){
                float2 v = make_float2(tVr[hn*64+o], tVi[hn*64+o]);
                float2 p = cmul(v, S255[h*64+o]);
                acc2.x += p.x; acc2.y += p.y;
            }
            if (tail_n >= 1024){
                out_tail[hn]       = acc2.x;
                out_tail[512 + hn] = acc2.y;
            } else if (tail_n >= 512){
                out_tail[hn] = acc2.x;
            }
        }
    }

    f32x4 acc[2][2];
    #pragma unroll
    for (int i=0;i<2;++i)
        #pragma unroll
        for (int j=0;j<2;++j) acc[i][j] = (f32x4){0.f,0.f,0.f,0.f};
    const int c0r = tid >> 2;
    const int c0s = tid & 3;
    for (int k0 = 0; k0 < K; k0 += BK){
        uint4 av = *(const uint4*)&A [(bm + c0r)*K + k0 + c0s*8];
        uint4 bv = *(const uint4*)&Bt[(bn + c0r)*K + k0 + c0s*8];
        __syncthreads();
        *(uint4*)&As[c0r*ASTR + c0s*8] = av;
        *(uint4*)&Bs[c0r*ASTR + c0s*8] = bv;
        __syncthreads();
        short8 af[2], bfv[2];
        #pragma unroll
        for (int f=0; f<2; ++f){
            af[f]  = *(const short8*)&As[(wr + f*16 + ml)*ASTR + quad*8];
            bfv[f] = *(const short8*)&Bs[(wc + f*16 + ml)*ASTR + quad*8];
        }
        #pragma unroll
        for (int i=0;i<2;++i)
            #pragma unroll
            for (int j=0;j<2;++j)
                acc[i][j] = __builtin_amdgcn_mfma_f32_16x16x32_bf16(af[i], bfv[j], acc[i][j], 0,0,0);
    }
    #pragma unroll
    for (int i=0;i<2;++i){
        #pragma unroll
        for (int j=0;j<2;++j){
            const int gcol = bn + wc + j*16 + ml;
            const float bsv = bias[gcol];
            #pragma unroll
            for (int r=0;r<4;++r){
                const int grow = bm + wr + i*16 + quad*4 + r;
                float val = acc[i][j][r] + bsv;
                if (ACT == 2){
                    float v1 = __shfl_down(val, 1);
                    float v2 = __shfl_down(val, 2);
                    float v3 = __shfl_down(val, 3);
                    if ((l & 3) == 0){
                        int hd = gcol >> 2;
                        XCo[grow*HD + hd] = make_float2(val, v1);
                        float m2 = v2*v2 + v3*v3;
                        float s = sqrtf(m2)/(1.f + m2);
                        Ao[grow*HD + hd] = make_float2(v2*s, v3*s);
                    }
                } else if (ACT == 1){
                    val *= 1.f/(1.f + expf(-val));
                    Cb[grow*N + gcol] = f2bf(val);
                } else {
                    Cf[grow*N + gcol] = val;
                }
            }
        }
    }
}

// ---------- fused uext + parallel scan; writes Sb (bf16, hr-layout) + S255 fp32 ----------
__global__ __launch_bounds__(512) void upscan_kernel(const float2* __restrict__ Vinv,
        const float* __restrict__ hidr, const float* __restrict__ him,
        const float2* __restrict__ XC, const float2* __restrict__ Aseq,
        ushort* __restrict__ Sb, float2* __restrict__ S255){
    __shared__ float4 buf[2][2][LSEQ];
    __shared__ float2 vrow[2][64];
    __shared__ float2 inu[2];
    const int b = blockIdx.x;
    const int tid = threadIdx.x;
    const int g = tid >> 8, m = tid & 255;
    const int hn = b*2 + g;
    const int h = hn >> 6;
    if (m < 64) vrow[g][m] = Vinv[hn*64 + m];
    __syncthreads();
    float2 acc = make_float2(0.f, 0.f);
    const float2* xrow = &XC[m*HD + h*64];
    #pragma unroll 8
    for (int o=0;o<64;++o){
        float2 p = cmul(vrow[g][o], xrow[o]);
        acc.x += p.x; acc.y += p.y;
    }
    if (m == 0){
        float2 i0 = make_float2(0.f, 0.f);
        #pragma unroll 8
        for (int o=0;o<64;++o){
            float2 hv = make_float2(hidr[h*64+o], him[h*64+o]);
            float2 p = cmul(vrow[g][o], hv);
            i0.x += p.x; i0.y += p.y;
        }
        inu[g] = i0;
    }
    float2 a = Aseq[m*HD + hn];
    buf[0][g][m] = make_float4(a.x, a.y, acc.x, acc.y);
    __syncthreads();
    int pb = 0;
    #pragma unroll
    for (int d = 1; d < LSEQ; d <<= 1){
        float4 cur = buf[pb][g][m];
        float4 o2 = cur;
        if (m >= d){
            float4 prev = buf[pb][g][m-d];
            float2 cA = make_float2(cur.x, cur.y), cU = make_float2(cur.z, cur.w);
            float2 pA = make_float2(prev.x, prev.y), pU = make_float2(prev.z, prev.w);
            float2 nA = cmul(cA, pA);
            float2 nU = cmul(cA, pU);
            nU.x += cU.x; nU.y += cU.y;
            o2 = make_float4(nA.x, nA.y, nU.x, nU.y);
        }
        buf[pb^1][g][m] = o2;
        pb ^= 1;
        __syncthreads();
    }
    float4 t = buf[pb][g][m];
    float2 init = inu[g];
    float2 st = cmul(make_float2(t.x, t.y), init);
    st.x += t.z; st.y += t.w;
    Sb[m*DIMN + hn*2]   = f2bf(st.x);
    Sb[m*DIMN + hn*2+1] = f2bf(st.y);
    if (m == LSEQ-1) S255[hn] = st;
}

// ---------- fallback-only kernels ----------
__global__ __launch_bounds__(256) void vmul_kernel(const float* __restrict__ Vr,
                            const float* __restrict__ Vi,
                            const float2* __restrict__ S, ushort* __restrict__ hrb,
                            float* __restrict__ out_tail, int tail_n){
    int g = blockIdx.x*256 + threadIdx.x;
    int m = g >> 9, hn = g & 511;
    int h = hn >> 6;
    const float* vr = &Vr[hn*64];
    const float* vi = &Vi[hn*64];
    const float2* srow = &S[m*HD + h*64];
    float2 acc = make_float2(0.f, 0.f);
    #pragma unroll 8
    for (int o=0;o<64;++o){
        float2 v = make_float2(vr[o], vi[o]);
        float2 p = cmul(v, srow[o]);
        acc.x += p.x; acc.y += p.y;
    }
    hrb[m*DIMN + hn*2]   = f2bf(acc.x);
    hrb[m*DIMN + hn*2+1] = f2bf(acc.y);
    if (m == LSEQ-1){
        if (tail_n >= 1024){
            out_tail[hn]       = acc.x;
            out_tail[512 + hn] = acc.y;
        } else if (tail_n >= 512){
            out_tail[hn] = acc.x;
        }
    }
}

__global__ __launch_bounds__(512) void upscan_f32_kernel(const float2* __restrict__ Vinv,
        const float* __restrict__ hidr, const float* __restrict__ him,
        const float2* __restrict__ XC, const float2* __restrict__ Aseq,
        float2* __restrict__ S){
    __shared__ float4 buf[2][2][LSEQ];
    __shared__ float2 vrow[2][64];
    __shared__ float2 inu[2];
    const int b = blockIdx.x;
    const int tid = threadIdx.x;
    const int g = tid >> 8, m = tid & 255;
    const int hn = b*2 + g;
    const int h = hn >> 6;
    if (m < 64) vrow[g][m] = Vinv[hn*64 + m];
    __syncthreads();
    float2 acc = make_float2(0.f, 0.f);
    const float2* xrow = &XC[m*HD + h*64];
    #pragma unroll 8
    for (int o=0;o<64;++o){
        float2 p = cmul(vrow[g][o], xrow[o]);
        acc.x += p.x; acc.y += p.y;
    }
    if (m == 0){
        float2 i0 = make_float2(0.f, 0.f);
        #pragma unroll 8
        for (int o=0;o<64;++o){
            float2 hv = make_float2(hidr[h*64+o], him[h*64+o]);
            float2 p = cmul(vrow[g][o], hv);
            i0.x += p.x; i0.y += p.y;
        }
        inu[g] = i0;
    }
    float2 a = Aseq[m*HD + hn];
    buf[0][g][m] = make_float4(a.x, a.y, acc.x, acc.y);
    __syncthreads();
    int pb = 0;
    #pragma unroll
    for (int d = 1; d < LSEQ; d <<= 1){
        float4 cur = buf[pb][g][m];
        float4 o2 = cur;
        if (m >= d){
            float4 prev = buf[pb][g][m-d];
            float2 cA = make_float2(cur.x, cur.y), cU = make_float2(cur.z, cur.w);
            float2 pA = make_float2(prev.x, prev.y), pU = make_float2(prev.z, prev.w);
            float2 nA = cmul(cA, pA);
            float2 nU = cmul(cA, pU);
            nU.x += cU.x; nU.y += cU.y;
            o2 = make_float4(nA.x, nA.y, nU.x, nU.y);
        }
        buf[pb^1][g][m] = o2;
        pb ^= 1;
        __syncthreads();
    }
    float4 t = buf[pb][g][m];
    float2 init = inu[g];
    float2 st = cmul(make_float2(t.x, t.y), init);
    st.x += t.z; st.y += t.w;
    S[m*HD + hn] = st;
}

extern "C" void kernel_launch(void* const* d_in, const int* in_sizes, int n_in,
                              void* d_out, int out_size, void* d_ws, size_t ws_size,
                              hipStream_t stream) {
    const float* x      = (const float*)d_in[0];
    const float* hidr   = (const float*)d_in[1];
    const float* hidi   = (const float*)d_in[2];
    const float* w_in1  = (const float*)d_in[3];
    const float* b_in1  = (const float*)d_in[4];
    const float* w_in2  = (const float*)d_in[5];
    const float* b_in2  = (const float*)d_in[6];
    const float* w_out1 = (const float*)d_in[7];
    const float* b_out1 = (const float*)d_in[8];
    const float* w_out2 = (const float*)d_in[9];
    const float* b_out2 = (const float*)d_in[10];
    const float* Vr     = (const float*)d_in[11];
    const float* Vi     = (const float*)d_in[12];
    float* out = (float*)d_out;
    const int tail_n = out_size - LSEQ*DIMN;
    char* ws = (char*)d_ws;

    if (ws_size >= 14946304u){
        // lifetime-aliased layout (no w1t/x_bf in 5-dispatch chain):
        //   Vinv  [0, 256K)            D1(inv)->D3
        //   w2t   [256K, 4.25M)        D1->D2
        //   W3bt  [4.25M, 6.25M)       D1->D4
        //   w4t   [6.25M, 8.25M)       D1->D5
        //   XC    [8.25M, 9.25M)       D2->D3
        //   Aseq  [9.25M, 10.25M)      D2->D3
        //   S255  [10.25M, +4K)        D3->D4
        //   t1_bf [10.75M, 11.25M)     D1->D2   } reused D3+: Sb
        //   y1_bf [11.25M, 11.75M)     D4->D5
        float2* Vinv  = (float2*)(ws + 0);
        ushort* w2t   = (ushort*)(ws + 262144);
        ushort* W3bt  = (ushort*)(ws + 4456448);
        ushort* w4t   = (ushort*)(ws + 6553600);
        float2* XC    = (float2*)(ws + 8650752);
        float2* Aseq  = (float2*)(ws + 9699328);
        float2* S255  = (float2*)(ws + 10747904);
        ushort* t1_bf = (ushort*)(ws + 11272192);
        ushort* y1_bf = (ushort*)(ws + 11796480);
        ushort* Sb    = t1_bf;

        // D1: mix1 — gemm1(direct fp32) + inv(setprio) + w2t + w4t + W3eff
        mix1_kernel<<<2600, 512, 0, stream>>>(x, w_in1, w_in2, w_out1, w_out2,
                                              Vr, Vi, b_in1, t1_bf, w2t, W3bt, w4t, Vinv);
        // D2: gemm2 (K-split, 256 blocks)
        gemm_ks<2,4><<<256, 512, 0, stream>>>(t1_bf, w2t, b_in2, nullptr, nullptr,
                XC, Aseq, LSEQ, 2048, nullptr, nullptr, nullptr, nullptr, 0);
        // D3: upscan
        upscan_kernel<<<256, 512, 0, stream>>>(Vinv, hidr, hidi, XC, Aseq, Sb, S255);
        // D4: gemm3 + hidden_next tail
        gemm_ks<1,8><<<257, 512, 0, stream>>>(Sb, W3bt, b_out1, nullptr, y1_bf,
                nullptr, nullptr, LSEQ, DIMN, Vr, Vi, S255, out + LSEQ*DIMN, tail_n);
        // D5: gemm4
        gemm_ks<0,8><<<256, 512, 0, stream>>>(y1_bf, w4t, b_out2, out, nullptr,
                nullptr, nullptr, LSEQ, DIMN, nullptr, nullptr, nullptr, nullptr, 0);
    } else {
        // ---- R14 fallback: serial prep + full vmul path ----
        float2* Vinv  = (float2*)(ws + 0);
        ushort* wt    = (ushort*)(ws + 262144);
        ushort* x_bf  = (ushort*)(ws + 4456448);
        ushort* t1_bf = (ushort*)(ws + 4980736);
        float2* XC    = (float2*)(ws + 5505024);
        float2* Aseq  = (float2*)(ws + 6553600);
        float2* S     = (float2*)(ws + 7602176);
        ushort* y1_bf = x_bf;
        ushort* hr_bf = t1_bf;

        inv_kernel<<<NH, 512, 0, stream>>>(Vr, Vi, Vinv);
        cvt_bf16_kernel<<<LSEQ*DIMN/4/256, 256, 0, stream>>>(x, x_bf, LSEQ*DIMN/4);
        transpose_cvt<<<dim3(32,32), 256, 0, stream>>>(w_in1, wt, DIMN, DIMN);
        gemm_bt<1><<<dim3(16,4), 256, 0, stream>>>(x_bf, wt, b_in1, nullptr, t1_bf,
                nullptr, nullptr, LSEQ, DIMN, DIMN, nullptr, nullptr, nullptr, nullptr, 0);
        transpose_cvt<<<dim3(64,32), 256, 0, stream>>>(w_in2, wt, DIMN, 2048);
        gemm_bt<2><<<dim3(32,4), 256, 0, stream>>>(t1_bf, wt, b_in2, nullptr, nullptr,
                XC, Aseq, LSEQ, 2048, DIMN, nullptr, nullptr, nullptr, nullptr, 0);
        upscan_f32_kernel<<<256, 512, 0, stream>>>(Vinv, hidr, hidi, XC, Aseq, S);
        vmul_kernel<<<LSEQ*HD/256, 256, 0, stream>>>(Vr, Vi, S, hr_bf, out + LSEQ*DIMN, tail_n);
        transpose_cvt<<<dim3(32,32), 256, 0, stream>>>(w_out1, wt, DIMN, DIMN);
        gemm_bt<1><<<dim3(16,4), 256, 0, stream>>>(hr_bf, wt, b_out1, nullptr, y1_bf,
                nullptr, nullptr, LSEQ, DIMN, DIMN, nullptr, nullptr, nullptr, nullptr, 0);
        transpose_cvt<<<dim3(32,32), 256, 0, stream>>>(w_out2, wt, DIMN, DIMN);
        gemm_bt<0><<<dim3(16,4), 256, 0, stream>>>(y1_bf, wt, b_out2, out, nullptr,
                nullptr, nullptr, LSEQ, DIMN, DIMN, nullptr, nullptr, nullptr, nullptr, 0);
    }
}